// Round 1
// 204.541 us; speedup vs baseline: 1.0040x; 1.0040x over previous
//
#include <hip/hip_runtime.h>
#include <hip/hip_bf16.h>

typedef unsigned short u16;
typedef unsigned int u32;
typedef __attribute__((ext_vector_type(8))) short short8;
typedef __attribute__((ext_vector_type(4))) float f32x4;

__device__ __forceinline__ u16 f2bf(float f) {
    union { float f; unsigned u; } v; v.f = f;
    unsigned r = v.u + 0x7fffu + ((v.u >> 16) & 1u);
    return (u16)(r >> 16);
}

__device__ __forceinline__ float fexp2(float x) {
#if __has_builtin(__builtin_amdgcn_exp2f)
    return __builtin_amdgcn_exp2f(x);
#else
    return __expf(x * 0.6931471805599453f);
#endif
}

// ---------------------------------------------------------------------------
// DPP 16-lane butterfly (r15): __shfl_xor lowers to ds_swizzle (~5.8 cyc DS);
// DPP row ops fuse into the max/add as ONE full-rate VALU op. Masks
// {1,2,7,15} (quad_perm[1,0,3,2]=0xB1, quad_perm[2,3,0,1]=0x4E,
// row_half_mirror=0x141, row_mirror=0x140) are GF(2)-independent -> valid
// butterfly over each contiguous 16-lane row (= our quad*16+l15 groups).
// ---------------------------------------------------------------------------
template <int CTRL>
__device__ __forceinline__ float fdpp(float x) {
    int xi = __builtin_bit_cast(int, x);
    int r = __builtin_amdgcn_update_dpp(0, xi, CTRL, 0xF, 0xF, true);
    return __builtin_bit_cast(float, r);
}
__device__ __forceinline__ float dpp_max16(float m) {
    m = fmaxf(m, fdpp<0xB1>(m));   // xor 1
    m = fmaxf(m, fdpp<0x4E>(m));   // xor 2
    m = fmaxf(m, fdpp<0x141>(m));  // xor 7 (row_half_mirror)
    m = fmaxf(m, fdpp<0x140>(m));  // xor 15 (row_mirror)
    return m;
}
__device__ __forceinline__ float dpp_sum16(float s) {
    s += fdpp<0xB1>(s);
    s += fdpp<0x4E>(s);
    s += fdpp<0x141>(s);
    s += fdpp<0x140>(s);
    return s;
}

// ---------------------------------------------------------------------------
// fp8 e4m3 pack/unpack (P pre-scaled x256; r9-r13 absmax 0.078).
// ---------------------------------------------------------------------------
#if __has_builtin(__builtin_amdgcn_cvt_pk_fp8_f32) && \
    __has_builtin(__builtin_amdgcn_cvt_f32_fp8)
#define FP8_HW 1
#else
#define FP8_HW 0
#endif

#if !FP8_HW
__device__ __forceinline__ u32 sw_fp8(float x) {  // x in [0, 448]
    union { float f; u32 u; } v; v.f = x;
    int E = (int)(v.u >> 23) - 127;
    if (x < 0.001953125f) return 0;
    if (E < -6) return (u32)(x * 512.0f + 0.5f);
    u32 m = v.u & 0x7fffffu;
    u32 r = (m + 0x80000u) >> 20;
    u32 bits = ((u32)(E + 7) << 3) + r;
    return bits > 0x7eu ? 0x7eu : bits;
}
__device__ __forceinline__ float sw_fp8d(u32 b) {
    u32 e = (b >> 3) & 15u, m = b & 7u;
    if (e == 0) return (float)m * 0.001953125f;
    union { u32 u; float f; } v; v.u = ((e + 120u) << 23) | (m << 20);
    return v.f;
}
#endif

__device__ __forceinline__ u32 fp8x4_pack(float p0, float p1, float p2, float p3) {
#if FP8_HW
    u32 v = (u32)__builtin_amdgcn_cvt_pk_fp8_f32(p0, p1, 0, false);
    v = (u32)__builtin_amdgcn_cvt_pk_fp8_f32(p2, p3, (int)v, true);
    return v;
#else
    return sw_fp8(p0) | (sw_fp8(p1) << 8) | (sw_fp8(p2) << 16) | (sw_fp8(p3) << 24);
#endif
}

#if FP8_HW
#define FP8_DEC(v, s) __builtin_amdgcn_cvt_f32_fp8((int)(v), (s))
#else
#define FP8_DEC(v, s) sw_fp8d(((v) >> ((s) * 8)) & 0xffu)
#endif

// async 16B global->LDS DMA (m97 pattern).
__device__ __forceinline__ void async_cp16(const u16* g, u16* l) {
    __builtin_amdgcn_global_load_lds(
        (const __attribute__((address_space(1))) void*)g,
        (__attribute__((address_space(3))) void*)l, 16, 0, 0);
}

// ---------------------------------------------------------------------------
// XOR-swizzled LDS GEMM cores, BK=64 (r13; zero SQ_LDS_BANK_CONFLICT).
// ---------------------------------------------------------------------------
__device__ __forceinline__ short8 mfma_ld(const u16* base, int off) {
    return *(const short8*)&base[off];
}

// 128x128x512: A [128,512] bf16 rm, B^T [128,512] bf16 rm (computes A.B^T).
__device__ __forceinline__ void gemm512(const u16* __restrict__ A,
                                        const u16* __restrict__ B,
                                        u16* As, u16* Bs,
                                        f32x4 acc[4][4], int tid) {
    const int lane = tid & 63, w = tid >> 6;
    const int quad = lane >> 4, l15 = lane & 15;
    const int wm = tid >> 7, wn = (tid >> 6) & 1;
    const int Gw = lane ^ ((lane >> 3) & 7);
    const int srow = Gw >> 3;
    const int scol = (Gw & 7) * 8;
    const int rl = l15 & 7;
    const int winl = l15 >> 3;
    int Pr[2];
#pragma unroll
    for (int h = 0; h < 2; h++)
        Pr[h] = (rl * 8 + ((quad + h * 4) ^ rl)) * 8;
    const int winA0 = (wm * 64) >> 3, winB0 = (wn * 64) >> 3;
    for (int k0 = 0; k0 < 512; k0 += 64) {
        __syncthreads();
#pragma unroll
        for (int t = 0; t < 4; t++) {
            int win = w * 4 + t;
            async_cp16(A + (size_t)(win * 8 + srow) * 512 + k0 + scol,
                       As + win * 512);
            async_cp16(B + (size_t)(win * 8 + srow) * 512 + k0 + scol,
                       Bs + win * 512);
        }
        __syncthreads();
#pragma unroll
        for (int h = 0; h < 2; h++) {
            short8 af[4], bfr[4];
#pragma unroll
            for (int i = 0; i < 4; i++)
                af[i] = mfma_ld(As, (winA0 + i * 2 + winl) * 512 + Pr[h]);
#pragma unroll
            for (int j = 0; j < 4; j++)
                bfr[j] = mfma_ld(Bs, (winB0 + j * 2 + winl) * 512 + Pr[h]);
#pragma unroll
            for (int i = 0; i < 4; i++)
#pragma unroll
                for (int j = 0; j < 4; j++)
                    acc[i][j] = __builtin_amdgcn_mfma_f32_16x16x32_bf16(
                        af[i], bfr[j], acc[i][j], 0, 0, 0);
        }
    }
}

// 64x128x512 variant (A 64 rows). As: 4096 u16, Bs: 8192 u16.
__device__ __forceinline__ void gemm512_r64(const u16* __restrict__ A,
                                            const u16* __restrict__ B,
                                            u16* As, u16* Bs,
                                            f32x4 acc[2][4], int tid) {
    const int lane = tid & 63, w = tid >> 6;
    const int quad = lane >> 4, l15 = lane & 15;
    const int wm = tid >> 7, wn = (tid >> 6) & 1;
    const int Gw = lane ^ ((lane >> 3) & 7);
    const int srow = Gw >> 3;
    const int scol = (Gw & 7) * 8;
    const int rl = l15 & 7;
    const int winl = l15 >> 3;
    int Pr[2];
#pragma unroll
    for (int h = 0; h < 2; h++)
        Pr[h] = (rl * 8 + ((quad + h * 4) ^ rl)) * 8;
    const int winA0 = (wm * 32) >> 3, winB0 = (wn * 64) >> 3;
    for (int k0 = 0; k0 < 512; k0 += 64) {
        __syncthreads();
#pragma unroll
        for (int t = 0; t < 2; t++) {
            int win = w * 2 + t;
            async_cp16(A + (size_t)(win * 8 + srow) * 512 + k0 + scol,
                       As + win * 512);
        }
#pragma unroll
        for (int t = 0; t < 4; t++) {
            int win = w * 4 + t;
            async_cp16(B + (size_t)(win * 8 + srow) * 512 + k0 + scol,
                       Bs + win * 512);
        }
        __syncthreads();
#pragma unroll
        for (int h = 0; h < 2; h++) {
            short8 af[2], bfr[4];
#pragma unroll
            for (int i = 0; i < 2; i++)
                af[i] = mfma_ld(As, (winA0 + i * 2 + winl) * 512 + Pr[h]);
#pragma unroll
            for (int j = 0; j < 4; j++)
                bfr[j] = mfma_ld(Bs, (winB0 + j * 2 + winl) * 512 + Pr[h]);
#pragma unroll
            for (int i = 0; i < 2; i++)
#pragma unroll
                for (int j = 0; j < 4; j++)
                    acc[i][j] = __builtin_amdgcn_mfma_f32_16x16x32_bf16(
                        af[i], bfr[j], acc[i][j], 0, 0, 0);
        }
    }
}

// ---------------------------------------------------------------------------
// Fused prep: [0,4096) convert X->bf16; [4096,5120) transpose weights;
// 5120: zero Sg (per-launch, graph-safe).
// ---------------------------------------------------------------------------
__global__ void prep(const float* __restrict__ X, const float* __restrict__ W0,
                     const float* __restrict__ W1, const float* __restrict__ W2,
                     const float* __restrict__ W3, u16* __restrict__ Xb,
                     u16* __restrict__ T0, u16* __restrict__ T1,
                     u16* __restrict__ T2, u16* __restrict__ T3,
                     float* __restrict__ Sg) {
    __shared__ float tile[32][33];
    int id = blockIdx.x, tid = threadIdx.x;
    if (id == 5120) {
        float4 z = {0.f, 0.f, 0.f, 0.f};
#pragma unroll
        for (int t = 0; t < 8; t++) ((float4*)Sg)[tid + t * 256] = z;
        return;
    }
    if (id < 4096) {
        int idx = (id * 256 + tid) * 4;
        float4 v = *(const float4*)&X[idx];
        ushort4 o;
        o.x = f2bf(v.x); o.y = f2bf(v.y); o.z = f2bf(v.z); o.w = f2bf(v.w);
        *(ushort4*)&Xb[idx] = o;
        return;
    }
    int t = id - 4096;
    int z = t >> 8, rem = t & 255;
    int bo_ = (rem & 15) * 32, bi = (rem >> 4) * 32;
    const float* src; u16* dst;
    switch (z) {
        case 0: src = W0; dst = T0; break;
        case 1: src = W1; dst = T1; break;
        case 2: src = W2; dst = T2; break;
        default: src = W3; dst = T3; break;
    }
    int tx = tid & 31, ty = tid >> 5;
#pragma unroll
    for (int s = 0; s < 4; s++) {
        int i = bi + ty + s * 8;
        tile[ty + s * 8][tx] = src[i * 512 + bo_ + tx];
    }
    __syncthreads();
#pragma unroll
    for (int s = 0; s < 4; s++) {
        int o = bo_ + ty + s * 8;
        dst[o * 512 + bi + tx] = f2bf(tile[tx][ty + s * 8]);
    }
}

// ---------------------------------------------------------------------------
// Fused QKV projection. z==0 (Q) scaled by log2(e) -> base-2 score domain.
// ---------------------------------------------------------------------------
__global__ __launch_bounds__(256) void gemm_qkv(
    const u16* __restrict__ Xb, const u16* __restrict__ Wall,
    const float* __restrict__ bq, const float* __restrict__ bk,
    const float* __restrict__ bv, u16* __restrict__ Qall) {
    __shared__ __align__(16) u16 As[8192];
    __shared__ __align__(16) u16 Bs[8192];
    int tid = threadIdx.x;
    int m0 = blockIdx.x * 128, n0 = blockIdx.y * 128, z = blockIdx.z;
    const u16* Bt = Wall + (size_t)z * 262144 + (size_t)n0 * 512;
    const float* bias = (z == 0) ? bq : (z == 1) ? bk : bv;
    const float qs = (z == 0) ? 1.44269504088896340736f : 1.0f;
    u16* C = Qall + (size_t)z * 4194304;
    f32x4 acc[4][4];
#pragma unroll
    for (int i = 0; i < 4; i++)
#pragma unroll
        for (int j = 0; j < 4; j++) acc[i][j] = (f32x4){0.f, 0.f, 0.f, 0.f};
    gemm512(Xb + (size_t)m0 * 512, Bt, As, Bs, acc, tid);
    int lane = tid & 63, quad = lane >> 4, l15 = lane & 15;
    int wm = tid >> 7, wn = (tid >> 6) & 1;
#pragma unroll
    for (int j = 0; j < 4; j++) {
        int n = n0 + wn * 64 + j * 16 + l15;
        float bvv = bias[n];
#pragma unroll
        for (int i = 0; i < 4; i++)
#pragma unroll
            for (int rg = 0; rg < 4; rg++) {
                int m = m0 + wm * 64 + i * 16 + quad * 4 + rg;
                C[(size_t)m * 512 + n] = f2bf((acc[i][j][rg] + bvv) * qs);
            }
    }
}

// ---------------------------------------------------------------------------
// Staging helpers for the 8-phase 256x256 attention pass-1 (T3+T4 schedule).
// Half-tiles: A-half(ih) = wins wm'*16 + ih*8 + [0,8); B-half(jh) = wins
// wn'*8 + jh*4 + [0,4). Each wave stages 2 wins (1 KiB each) per half.
// LDS dest is wave-uniform base + lane*16 (global_load_lds constraint);
// the XOR swizzle lives in the per-lane GLOBAL source address (m173 pattern).
// ---------------------------------------------------------------------------
__device__ __forceinline__ void stage_half_A(const u16* __restrict__ Q,
                                             u16* dst, int kn, int half,
                                             int wid, int srow, int scol) {
#pragma unroll
    for (int c = 0; c < 2; c++) {
        int win = (wid >> 2) * 16 + half * 8 + (wid & 3) * 2 + c;
        async_cp16(Q + (size_t)(win * 8 + srow) * 512 + kn + scol,
                   dst + win * 512);
    }
}
__device__ __forceinline__ void stage_half_B(const u16* __restrict__ K,
                                             u16* dst, int kn, int half,
                                             int wid, int srow, int scol) {
#pragma unroll
    for (int c = 0; c < 2; c++) {
        int win = (wid >> 1) * 8 + half * 4 + (wid & 1) * 2 + c;
        async_cp16(K + (size_t)(win * 8 + srow) * 512 + kn + scol,
                   dst + win * 512);
    }
}

// ---------------------------------------------------------------------------
// Pass 1 v2 (r16): 256x256 score tile, 8 waves (2Mx4N), BK=64, 128 KiB LDS
// double-buffer, 8-phase schedule with COUNTED vmcnt (T3+T4) + setprio (T5).
// Per K-tile: 4 phases (ih,jh), each {12 ds_read_b128 | prefetch 1 half-tile
// (2 global_load_lds) -> s_barrier -> lgkmcnt(0) -> 16 MFMA}. Half-tiles of
// tile kt+1 issued A0@p0,B0@p0,B1@p1,A1@p2; waits: vmcnt(6)@p1 (ensures kt's
// A1), vmcnt(2)@p3 (ensures kt+1's A0,B0,B1) -- never drains to 0 in the
// loop. Epilogue identical math to r15: per-row 64-col-chunk max via DPP
// butterfly, P=exp2(s-Mt+8) fp8x4 value-major [g][tid], stats (Mt, L/256).
// Grid (16, 16, 2), 512 threads.
// ---------------------------------------------------------------------------
__global__ __launch_bounds__(512, 2) void attn_pass1p(
    const u16* __restrict__ Qb, const u16* __restrict__ Kb,
    float2* __restrict__ statsP, u32* __restrict__ Pbuf) {
    __shared__ __align__(16) u16 As[2][16384];
    __shared__ __align__(16) u16 Bs[2][16384];
    int tid = threadIdx.x;
    int mblk = blockIdx.x, nblk = blockIdx.y, b = blockIdx.z;
    const u16* Q = Qb + ((size_t)(b * 4096 + mblk * 256)) * 512;
    const u16* K = Kb + ((size_t)(b * 4096 + nblk * 256)) * 512;
    int lane = tid & 63, wid = tid >> 6;
    int quad = lane >> 4, l15 = lane & 15;
    int wm = wid >> 2, wn = wid & 3;
    int Gw = lane ^ ((lane >> 3) & 7);
    int srow = Gw >> 3, scol = (Gw & 7) * 8;
    int rl = l15 & 7, winl = l15 >> 3;
    int Pr[2];
#pragma unroll
    for (int h = 0; h < 2; h++)
        Pr[h] = (rl * 8 + ((quad + h * 4) ^ rl)) * 8;

    f32x4 acc[8][4];
#pragma unroll
    for (int i = 0; i < 8; i++)
#pragma unroll
        for (int j = 0; j < 4; j++) acc[i][j] = (f32x4){0.f, 0.f, 0.f, 0.f};

    // Prologue: stage tile 0 fully, single full drain (only one in kernel).
    stage_half_A(Q, &As[0][0], 0, 0, wid, srow, scol);
    stage_half_B(K, &Bs[0][0], 0, 0, wid, srow, scol);
    stage_half_B(K, &Bs[0][0], 0, 1, wid, srow, scol);
    stage_half_A(Q, &As[0][0], 0, 1, wid, srow, scol);
    asm volatile("s_waitcnt vmcnt(0)" ::: "memory");
    __builtin_amdgcn_s_barrier();
    asm volatile("" ::: "memory");

    for (int kt = 0; kt < 8; ++kt) {
        const u16* Ac = &As[kt & 1][0];
        const u16* Bc = &Bs[kt & 1][0];
        u16* An = &As[(kt + 1) & 1][0];
        u16* Bn = &Bs[(kt + 1) & 1][0];
        int kn = (kt + 1) * 64;
        bool pf = (kt < 7);
#pragma unroll
        for (int ph = 0; ph < 4; ++ph) {
            const int ih = ph >> 1, jh = ph & 1;
            short8 af[4][2], bfr[2][2];
#pragma unroll
            for (int h = 0; h < 2; h++) {
#pragma unroll
                for (int ii = 0; ii < 4; ii++)
                    af[ii][h] = mfma_ld(
                        Ac, (wm * 16 + ih * 8 + ii * 2 + winl) * 512 + Pr[h]);
#pragma unroll
                for (int jj = 0; jj < 2; jj++)
                    bfr[jj][h] = mfma_ld(
                        Bc, (wn * 8 + jh * 4 + jj * 2 + winl) * 512 + Pr[h]);
            }
            if (pf) {
                if (ph == 0) {
                    stage_half_A(Q, An, kn, 0, wid, srow, scol);
                    stage_half_B(K, Bn, kn, 0, wid, srow, scol);
                } else if (ph == 1) {
                    stage_half_B(K, Bn, kn, 1, wid, srow, scol);
                } else if (ph == 2) {
                    stage_half_A(Q, An, kn, 1, wid, srow, scol);
                }
            }
            if (ph == 1) {
                if (pf) asm volatile("s_waitcnt vmcnt(6)" ::: "memory");
                else    asm volatile("s_waitcnt vmcnt(0)" ::: "memory");
            }
            if (ph == 3) asm volatile("s_waitcnt vmcnt(2)" ::: "memory");
            asm volatile("" ::: "memory");
            __builtin_amdgcn_s_barrier();
            asm volatile("s_waitcnt lgkmcnt(0)" ::: "memory");
            __builtin_amdgcn_s_setprio(1);
#pragma unroll
            for (int h = 0; h < 2; h++)
#pragma unroll
                for (int ii = 0; ii < 4; ii++)
#pragma unroll
                    for (int jj = 0; jj < 2; jj++)
                        acc[ih * 4 + ii][jh * 2 + jj] =
                            __builtin_amdgcn_mfma_f32_16x16x32_bf16(
                                af[ii][h], bfr[jj][h],
                                acc[ih * 4 + ii][jh * 2 + jj], 0, 0, 0);
            __builtin_amdgcn_s_setprio(0);
            asm volatile("" ::: "memory");
            __builtin_amdgcn_s_barrier();
            asm volatile("" ::: "memory");
        }
    }

    // Epilogue: per (i,rg) row, chunk-max over the 64 cols (4 j-frags x 16
    // l15 lanes), P in fp8, stats write. No LDS use -> no barrier needed.
    u32* Pt = Pbuf + ((size_t)((b * 16 + mblk) * 16 + nblk)) * 16384;
    int ch = nblk * 4 + wn;
    float2* Sp = statsP + ((size_t)(b * 64 + ch)) * 4096;
    int mbase = mblk * 256 + wm * 128;
#pragma unroll
    for (int i = 0; i < 8; i++)
#pragma unroll
        for (int rg = 0; rg < 4; rg++) {
            float v0 = acc[i][0][rg], v1 = acc[i][1][rg];
            float v2 = acc[i][2][rg], v3 = acc[i][3][rg];
            float Mt = fmaxf(fmaxf(v0, v1), fmaxf(v2, v3));
            Mt = dpp_max16(Mt);  // uniform over the 16 l15 lanes
            float e8 = Mt - 8.0f;  // x256 pre-scale for fp8 range
            float p0 = fexp2(v0 - e8), p1 = fexp2(v1 - e8);
            float p2 = fexp2(v2 - e8), p3 = fexp2(v3 - e8);
            Pt[(i * 4 + rg) * 512 + tid] = fp8x4_pack(p0, p1, p2, p3);
            float L = dpp_sum16(p0 + p1 + p2 + p3);
            if (l15 == 0)
                Sp[mbase + i * 16 + quad * 4 + rg] =
                    make_float2(Mt, L * 0.00390625f);  // true L_ch
        }
}

// ---------------------------------------------------------------------------
// c = M + log2(Z) per row. Separate kernel (r10: fusing into colsum = 64x
// redundancy, +10us; r7: retained-array version spilled). grid 32 x 256.
// ---------------------------------------------------------------------------
__global__ void reduce_stats2(const float2* __restrict__ statsP,
                              float* __restrict__ cstat) {
    int t = blockIdx.x * 256 + threadIdx.x;
    int b = t >> 12, m = t & 4095;
    const float2* sp = statsP + (size_t)b * 64 * 4096 + m;
    float M = -INFINITY;
#pragma unroll 4
    for (int ch = 0; ch < 64; ch++) M = fmaxf(M, sp[(size_t)ch * 4096].x);
    float Z = 0.f;
#pragma unroll 4
    for (int ch = 0; ch < 64; ch++) {
        float2 p = sp[(size_t)ch * 4096];
        Z += p.y * fexp2(p.x - M);
    }
    cstat[t] = M + __log2f(Z);
}

// ---------------------------------------------------------------------------
// Weighted column sums v2 (matches pass-1 v2 256x256 Pbuf tiles):
// S[n] += sum_m P_fp8[m,n] * exp2(Mt[m]-8-c[m]). F-SKIP (2^-58): dropped
// mass/col <= 4096*256*2^-58 = 2^-38, scale err <= 3.6e-3.
// grid (nblk=16, mgrp=8 (2 mblks each), b=2), 512 threads: thread tid holds
// the SAME (m,n) cells it wrote in pass 1.
// ---------------------------------------------------------------------------
__global__ __launch_bounds__(512) void colsum(
    const u32* __restrict__ Pbuf, const float2* __restrict__ statsP,
    const float* __restrict__ cstat, float* __restrict__ Sg) {
    int tid = threadIdx.x, lane = tid & 63, wid = tid >> 6;
    int quad = lane >> 4, l15 = lane & 15;
    int wm = wid >> 2, wn = wid & 3;
    int nblk = blockIdx.x, mgrp = blockIdx.y, b = blockIdx.z;
    int ch = nblk * 4 + wn;
    const float2* Sp = statsP + ((size_t)(b * 64 + ch)) * 4096;
    const float* Cp = cstat + (size_t)b * 4096;
    float cp[4] = {0.f, 0.f, 0.f, 0.f};
    for (int mb = 0; mb < 2; mb++) {
        int mblk = mgrp * 2 + mb;
        const u32* Pt =
            Pbuf + ((size_t)((b * 16 + mblk) * 16 + nblk)) * 16384;
#pragma unroll
        for (int i = 0; i < 8; i++) {
            int r0 = mblk * 256 + wm * 128 + i * 16 + quad * 4;
            float4 s01 = *(const float4*)&Sp[r0];      // (M0,L0,M1,L1)
            float4 s23 = *(const float4*)&Sp[r0 + 2];  // (M2,L2,M3,L3)
            float4 cv = *(const float4*)&Cp[r0];
            float fv[4] = {fexp2(s01.x - 8.0f - cv.x),
                           fexp2(s01.z - 8.0f - cv.y),
                           fexp2(s23.x - 8.0f - cv.z),
                           fexp2(s23.z - 8.0f - cv.w)};
            float fm = fmaxf(fmaxf(fv[0], fv[1]), fmaxf(fv[2], fv[3]));
            if (fm > 3.469446951953614e-18f) {  // 2^-58: see header comment
#pragma unroll
                for (int rg = 0; rg < 4; rg++) {
                    u32 e = Pt[(i * 4 + rg) * 512 + tid];
                    cp[0] += FP8_DEC(e, 0) * fv[rg];
                    cp[1] += FP8_DEC(e, 1) * fv[rg];
                    cp[2] += FP8_DEC(e, 2) * fv[rg];
                    cp[3] += FP8_DEC(e, 3) * fv[rg];
                }
            }
        }
    }
#pragma unroll
    for (int j = 0; j < 4; j++) {
        float s = cp[j];
        s += __shfl_xor(s, 16);
        s += __shfl_xor(s, 32);
        if (lane < 16)
            atomicAdd(&Sg[b * 4096 + nblk * 256 + wn * 64 + j * 16 + l15], s);
    }
}

// ---------------------------------------------------------------------------
// Final: out = relu(BN((V*rowscale) . Wo^T + bo)) + X  (fp32 out)
// 64x128 tiles, grid (128, 4). m0 in [0,8192) == flat (b,m).
// ---------------------------------------------------------------------------
__global__ __launch_bounds__(256) void gemm_final(
    const u16* __restrict__ A, const u16* __restrict__ Bt,
    const float* __restrict__ Sg, const float* __restrict__ bo,
    const float* __restrict__ g, const float* __restrict__ bb,
    const float* __restrict__ mean, const float* __restrict__ var,
    const float* __restrict__ X, float* __restrict__ out) {
    __shared__ __align__(16) u16 As[4096];
    __shared__ __align__(16) u16 Bs[8192];
    int tid = threadIdx.x;
    int m0 = blockIdx.x * 64, n0 = blockIdx.y * 128;
    f32x4 acc[2][4];
#pragma unroll
    for (int i = 0; i < 2; i++)
#pragma unroll
        for (int j = 0; j < 4; j++) acc[i][j] = (f32x4){0.f, 0.f, 0.f, 0.f};
    gemm512_r64(A + (size_t)m0 * 512, Bt + (size_t)n0 * 512, As, Bs, acc, tid);
    int lane = tid & 63, quad = lane >> 4, l15 = lane & 15;
    int wm = tid >> 7, wn = (tid >> 6) & 1;
    float sc[2][4];
#pragma unroll
    for (int i = 0; i < 2; i++) {
        float4 s = *(const float4*)&Sg[m0 + wm * 32 + i * 16 + quad * 4];
        float v[4] = {s.x, s.y, s.z, s.w};
#pragma unroll
        for (int rg = 0; rg < 4; rg++) sc[i][rg] = v[rg] / (1e-9f + v[rg]);
    }
#pragma unroll
    for (int j = 0; j < 4; j++) {
        int n = n0 + wn * 64 + j * 16 + l15;
        float aj = rsqrtf(var[n] + 1e-5f) * g[n];
        float cj = bb[n] - mean[n] * aj;
        float bj = bo[n];
#pragma unroll
        for (int i = 0; i < 2; i++)
#pragma unroll
            for (int rg = 0; rg < 4; rg++) {
                int m = m0 + wm * 32 + i * 16 + quad * 4 + rg;
                float x = acc[i][j][rg] * sc[i][rg] + bj;
                float y = x * aj + cj;
                out[(size_t)m * 512 + n] = fmaxf(y, 0.f) + X[(size_t)m * 512 + n];
            }
    }
}

// ---------------------------------------------------------------------------
extern "C" void kernel_launch(void* const* d_in, const int* in_sizes, int n_in,
                              void* d_out, int out_size, void* d_ws, size_t ws_size,
                              hipStream_t stream) {
    const float* X  = (const float*)d_in[0];
    const float* Wq = (const float*)d_in[1];
    const float* Wk = (const float*)d_in[2];
    const float* Wv = (const float*)d_in[3];
    const float* Wo = (const float*)d_in[4];
    const float* bq = (const float*)d_in[5];
    const float* bk = (const float*)d_in[6];
    const float* bv = (const float*)d_in[7];
    const float* bo = (const float*)d_in[8];
    const float* g    = (const float*)d_in[9];
    const float* bb   = (const float*)d_in[10];
    const float* mean = (const float*)d_in[11];
    const float* var  = (const float*)d_in[12];
    float* out = (float*)d_out;

    char* ws = (char*)d_ws;
    u16* Xb  = (u16*)(ws + 0);                    // 8 MB
    u16* Wqt = (u16*)(ws + 8388608);              // 4x512KB (Wq,Wk,Wv,Wo)
    u16* Wot = (u16*)(ws + 9961472);
    u16* Qb  = (u16*)(ws + 10485760);             // Q,K,V contiguous 3x8MB
    u16* Kb  = (u16*)(ws + 18874368);
    u16* Vb  = (u16*)(ws + 27262976);
    float2* statsP = (float2*)(ws + 35651584);    // [b][64][4096] f2 = 4 MB
    float* Sg      = (float*)(ws + 39845888);     // 32 KB
    float* cstat   = (float*)(ws + 39878656);     // 32 KB
    u32* Pbuf      = (u32*)(ws + 39911424);       // 32 MB fp8 P

    prep<<<5121, 256, 0, stream>>>(X, Wq, Wk, Wv, Wo, Xb, Wqt, Wqt + 262144,
                                   Wqt + 524288, Wot, Sg);
    gemm_qkv<<<dim3(64, 4, 3), 256, 0, stream>>>(Xb, Wqt, bq, bk, bv, Qb);
    attn_pass1p<<<dim3(16, 16, 2), 512, 0, stream>>>(Qb, Kb, statsP, Pbuf);
    reduce_stats2<<<32, 256, 0, stream>>>(statsP, cstat);
    colsum<<<dim3(16, 8, 2), 512, 0, stream>>>(Pbuf, statsP, cstat, Sg);
    gemm_final<<<dim3(128, 4), 256, 0, stream>>>(Vb, Wot, Sg, bo, g, bb, mean, var,
                                                 X, out);
}

// Round 3
// 203.901 us; speedup vs baseline: 1.0071x; 1.0031x over previous
//
#include <hip/hip_runtime.h>
#include <hip/hip_bf16.h>

typedef unsigned short u16;
typedef unsigned int u32;
typedef __attribute__((ext_vector_type(8))) short short8;
typedef __attribute__((ext_vector_type(4))) float f32x4;
typedef __attribute__((ext_vector_type(4))) unsigned int u32x4;

__device__ __forceinline__ u16 f2bf(float f) {
    union { float f; unsigned u; } v; v.f = f;
    unsigned r = v.u + 0x7fffu + ((v.u >> 16) & 1u);
    return (u16)(r >> 16);
}

__device__ __forceinline__ float fexp2(float x) {
#if __has_builtin(__builtin_amdgcn_exp2f)
    return __builtin_amdgcn_exp2f(x);
#else
    return __expf(x * 0.6931471805599453f);
#endif
}

// ---------------------------------------------------------------------------
// DPP 16-lane butterfly (r15): __shfl_xor lowers to ds_swizzle (~5.8 cyc DS);
// DPP row ops fuse into the max/add as ONE full-rate VALU op. Masks
// {1,2,7,15} (quad_perm[1,0,3,2]=0xB1, quad_perm[2,3,0,1]=0x4E,
// row_half_mirror=0x141, row_mirror=0x140) are GF(2)-independent -> valid
// butterfly over each contiguous 16-lane row (= our quad*16+l15 groups).
// ---------------------------------------------------------------------------
template <int CTRL>
__device__ __forceinline__ float fdpp(float x) {
    int xi = __builtin_bit_cast(int, x);
    int r = __builtin_amdgcn_update_dpp(0, xi, CTRL, 0xF, 0xF, true);
    return __builtin_bit_cast(float, r);
}
__device__ __forceinline__ float dpp_max16(float m) {
    m = fmaxf(m, fdpp<0xB1>(m));   // xor 1
    m = fmaxf(m, fdpp<0x4E>(m));   // xor 2
    m = fmaxf(m, fdpp<0x141>(m));  // xor 7 (row_half_mirror)
    m = fmaxf(m, fdpp<0x140>(m));  // xor 15 (row_mirror)
    return m;
}
__device__ __forceinline__ float dpp_sum16(float s) {
    s += fdpp<0xB1>(s);
    s += fdpp<0x4E>(s);
    s += fdpp<0x141>(s);
    s += fdpp<0x140>(s);
    return s;
}

// ---------------------------------------------------------------------------
// fp8 e4m3 pack/unpack (P pre-scaled x256; r9-r13 absmax 0.078).
// ---------------------------------------------------------------------------
#if __has_builtin(__builtin_amdgcn_cvt_pk_fp8_f32) && \
    __has_builtin(__builtin_amdgcn_cvt_f32_fp8)
#define FP8_HW 1
#else
#define FP8_HW 0
#endif

#if !FP8_HW
__device__ __forceinline__ u32 sw_fp8(float x) {  // x in [0, 448]
    union { float f; u32 u; } v; v.f = x;
    int E = (int)(v.u >> 23) - 127;
    if (x < 0.001953125f) return 0;
    if (E < -6) return (u32)(x * 512.0f + 0.5f);
    u32 m = v.u & 0x7fffffu;
    u32 r = (m + 0x80000u) >> 20;
    u32 bits = ((u32)(E + 7) << 3) + r;
    return bits > 0x7eu ? 0x7eu : bits;
}
__device__ __forceinline__ float sw_fp8d(u32 b) {
    u32 e = (b >> 3) & 15u, m = b & 7u;
    if (e == 0) return (float)m * 0.001953125f;
    union { u32 u; float f; } v; v.u = ((e + 120u) << 23) | (m << 20);
    return v.f;
}
#endif

__device__ __forceinline__ u32 fp8x4_pack(float p0, float p1, float p2, float p3) {
#if FP8_HW
    u32 v = (u32)__builtin_amdgcn_cvt_pk_fp8_f32(p0, p1, 0, false);
    v = (u32)__builtin_amdgcn_cvt_pk_fp8_f32(p2, p3, (int)v, true);
    return v;
#else
    return sw_fp8(p0) | (sw_fp8(p1) << 8) | (sw_fp8(p2) << 16) | (sw_fp8(p3) << 24);
#endif
}

#if FP8_HW
#define FP8_DEC(v, s) __builtin_amdgcn_cvt_f32_fp8((int)(v), (s))
#else
#define FP8_DEC(v, s) sw_fp8d(((v) >> ((s) * 8)) & 0xffu)
#endif

// async 16B global->LDS DMA (m97 pattern).
__device__ __forceinline__ void async_cp16(const u16* g, u16* l) {
    __builtin_amdgcn_global_load_lds(
        (const __attribute__((address_space(1))) void*)g,
        (__attribute__((address_space(3))) void*)l, 16, 0, 0);
}

// ---------------------------------------------------------------------------
// XOR-swizzled LDS GEMM cores, BK=64 (r13; zero SQ_LDS_BANK_CONFLICT).
// ---------------------------------------------------------------------------
__device__ __forceinline__ short8 mfma_ld(const u16* base, int off) {
    return *(const short8*)&base[off];
}

// 128x128x512: A [128,512] bf16 rm, B^T [128,512] bf16 rm (computes A.B^T).
__device__ __forceinline__ void gemm512(const u16* __restrict__ A,
                                        const u16* __restrict__ B,
                                        u16* As, u16* Bs,
                                        f32x4 acc[4][4], int tid) {
    const int lane = tid & 63, w = tid >> 6;
    const int quad = lane >> 4, l15 = lane & 15;
    const int wm = tid >> 7, wn = (tid >> 6) & 1;
    const int Gw = lane ^ ((lane >> 3) & 7);
    const int srow = Gw >> 3;
    const int scol = (Gw & 7) * 8;
    const int rl = l15 & 7;
    const int winl = l15 >> 3;
    int Pr[2];
#pragma unroll
    for (int h = 0; h < 2; h++)
        Pr[h] = (rl * 8 + ((quad + h * 4) ^ rl)) * 8;
    const int winA0 = (wm * 64) >> 3, winB0 = (wn * 64) >> 3;
    for (int k0 = 0; k0 < 512; k0 += 64) {
        __syncthreads();
#pragma unroll
        for (int t = 0; t < 4; t++) {
            int win = w * 4 + t;
            async_cp16(A + (size_t)(win * 8 + srow) * 512 + k0 + scol,
                       As + win * 512);
            async_cp16(B + (size_t)(win * 8 + srow) * 512 + k0 + scol,
                       Bs + win * 512);
        }
        __syncthreads();
#pragma unroll
        for (int h = 0; h < 2; h++) {
            short8 af[4], bfr[4];
#pragma unroll
            for (int i = 0; i < 4; i++)
                af[i] = mfma_ld(As, (winA0 + i * 2 + winl) * 512 + Pr[h]);
#pragma unroll
            for (int j = 0; j < 4; j++)
                bfr[j] = mfma_ld(Bs, (winB0 + j * 2 + winl) * 512 + Pr[h]);
#pragma unroll
            for (int i = 0; i < 4; i++)
#pragma unroll
                for (int j = 0; j < 4; j++)
                    acc[i][j] = __builtin_amdgcn_mfma_f32_16x16x32_bf16(
                        af[i], bfr[j], acc[i][j], 0, 0, 0);
        }
    }
}

// 64x128x512 variant (A 64 rows). As: 4096 u16, Bs: 8192 u16.
__device__ __forceinline__ void gemm512_r64(const u16* __restrict__ A,
                                            const u16* __restrict__ B,
                                            u16* As, u16* Bs,
                                            f32x4 acc[2][4], int tid) {
    const int lane = tid & 63, w = tid >> 6;
    const int quad = lane >> 4, l15 = lane & 15;
    const int wm = tid >> 7, wn = (tid >> 6) & 1;
    const int Gw = lane ^ ((lane >> 3) & 7);
    const int srow = Gw >> 3;
    const int scol = (Gw & 7) * 8;
    const int rl = l15 & 7;
    const int winl = l15 >> 3;
    int Pr[2];
#pragma unroll
    for (int h = 0; h < 2; h++)
        Pr[h] = (rl * 8 + ((quad + h * 4) ^ rl)) * 8;
    const int winA0 = (wm * 32) >> 3, winB0 = (wn * 64) >> 3;
    for (int k0 = 0; k0 < 512; k0 += 64) {
        __syncthreads();
#pragma unroll
        for (int t = 0; t < 2; t++) {
            int win = w * 2 + t;
            async_cp16(A + (size_t)(win * 8 + srow) * 512 + k0 + scol,
                       As + win * 512);
        }
#pragma unroll
        for (int t = 0; t < 4; t++) {
            int win = w * 4 + t;
            async_cp16(B + (size_t)(win * 8 + srow) * 512 + k0 + scol,
                       Bs + win * 512);
        }
        __syncthreads();
#pragma unroll
        for (int h = 0; h < 2; h++) {
            short8 af[2], bfr[4];
#pragma unroll
            for (int i = 0; i < 2; i++)
                af[i] = mfma_ld(As, (winA0 + i * 2 + winl) * 512 + Pr[h]);
#pragma unroll
            for (int j = 0; j < 4; j++)
                bfr[j] = mfma_ld(Bs, (winB0 + j * 2 + winl) * 512 + Pr[h]);
#pragma unroll
            for (int i = 0; i < 2; i++)
#pragma unroll
                for (int j = 0; j < 4; j++)
                    acc[i][j] = __builtin_amdgcn_mfma_f32_16x16x32_bf16(
                        af[i], bfr[j], acc[i][j], 0, 0, 0);
        }
    }
}

// ---------------------------------------------------------------------------
// Fused prep: [0,4096) convert X->bf16; [4096,5120) transpose weights;
// 5120: zero Sg (per-launch, graph-safe).
// ---------------------------------------------------------------------------
__global__ void prep(const float* __restrict__ X, const float* __restrict__ W0,
                     const float* __restrict__ W1, const float* __restrict__ W2,
                     const float* __restrict__ W3, u16* __restrict__ Xb,
                     u16* __restrict__ T0, u16* __restrict__ T1,
                     u16* __restrict__ T2, u16* __restrict__ T3,
                     float* __restrict__ Sg) {
    __shared__ float tile[32][33];
    int id = blockIdx.x, tid = threadIdx.x;
    if (id == 5120) {
        float4 z = {0.f, 0.f, 0.f, 0.f};
#pragma unroll
        for (int t = 0; t < 8; t++) ((float4*)Sg)[tid + t * 256] = z;
        return;
    }
    if (id < 4096) {
        int idx = (id * 256 + tid) * 4;
        float4 v = *(const float4*)&X[idx];
        ushort4 o;
        o.x = f2bf(v.x); o.y = f2bf(v.y); o.z = f2bf(v.z); o.w = f2bf(v.w);
        *(ushort4*)&Xb[idx] = o;
        return;
    }
    int t = id - 4096;
    int z = t >> 8, rem = t & 255;
    int bo_ = (rem & 15) * 32, bi = (rem >> 4) * 32;
    const float* src; u16* dst;
    switch (z) {
        case 0: src = W0; dst = T0; break;
        case 1: src = W1; dst = T1; break;
        case 2: src = W2; dst = T2; break;
        default: src = W3; dst = T3; break;
    }
    int tx = tid & 31, ty = tid >> 5;
#pragma unroll
    for (int s = 0; s < 4; s++) {
        int i = bi + ty + s * 8;
        tile[ty + s * 8][tx] = src[i * 512 + bo_ + tx];
    }
    __syncthreads();
#pragma unroll
    for (int s = 0; s < 4; s++) {
        int o = bo_ + ty + s * 8;
        dst[o * 512 + bi + tx] = f2bf(tile[tx][ty + s * 8]);
    }
}

// ---------------------------------------------------------------------------
// Fused QKV projection. z==0 (Q) scaled by log2(e) -> base-2 score domain.
// ---------------------------------------------------------------------------
__global__ __launch_bounds__(256) void gemm_qkv(
    const u16* __restrict__ Xb, const u16* __restrict__ Wall,
    const float* __restrict__ bq, const float* __restrict__ bk,
    const float* __restrict__ bv, u16* __restrict__ Qall) {
    __shared__ __align__(16) u16 As[8192];
    __shared__ __align__(16) u16 Bs[8192];
    int tid = threadIdx.x;
    int m0 = blockIdx.x * 128, n0 = blockIdx.y * 128, z = blockIdx.z;
    const u16* Bt = Wall + (size_t)z * 262144 + (size_t)n0 * 512;
    const float* bias = (z == 0) ? bq : (z == 1) ? bk : bv;
    const float qs = (z == 0) ? 1.44269504088896340736f : 1.0f;
    u16* C = Qall + (size_t)z * 4194304;
    f32x4 acc[4][4];
#pragma unroll
    for (int i = 0; i < 4; i++)
#pragma unroll
        for (int j = 0; j < 4; j++) acc[i][j] = (f32x4){0.f, 0.f, 0.f, 0.f};
    gemm512(Xb + (size_t)m0 * 512, Bt, As, Bs, acc, tid);
    int lane = tid & 63, quad = lane >> 4, l15 = lane & 15;
    int wm = tid >> 7, wn = (tid >> 6) & 1;
#pragma unroll
    for (int j = 0; j < 4; j++) {
        int n = n0 + wn * 64 + j * 16 + l15;
        float bvv = bias[n];
#pragma unroll
        for (int i = 0; i < 4; i++)
#pragma unroll
            for (int rg = 0; rg < 4; rg++) {
                int m = m0 + wm * 64 + i * 16 + quad * 4 + rg;
                C[(size_t)m * 512 + n] = f2bf((acc[i][j][rg] + bvv) * qs);
            }
    }
}

// ---------------------------------------------------------------------------
// Staging helpers for the 8-phase 256x256 attention pass-1 (T3+T4 schedule).
// Half-tiles: A-half(ih) = wins wm'*16 + ih*8 + [0,8); B-half(jh) = wins
// wn'*8 + jh*4 + [0,4). Each wave stages 2 wins (1 KiB each) per half.
// LDS dest is wave-uniform base + lane*16 (global_load_lds constraint);
// the XOR swizzle lives in the per-lane GLOBAL source address (m173 pattern).
// ---------------------------------------------------------------------------
__device__ __forceinline__ void stage_half_A(const u16* __restrict__ Q,
                                             u16* dst, int kn, int half,
                                             int wid, int srow, int scol) {
#pragma unroll
    for (int c = 0; c < 2; c++) {
        int win = (wid >> 2) * 16 + half * 8 + (wid & 3) * 2 + c;
        async_cp16(Q + (size_t)(win * 8 + srow) * 512 + kn + scol,
                   dst + win * 512);
    }
}
__device__ __forceinline__ void stage_half_B(const u16* __restrict__ K,
                                             u16* dst, int kn, int half,
                                             int wid, int srow, int scol) {
#pragma unroll
    for (int c = 0; c < 2; c++) {
        int win = (wid >> 1) * 8 + half * 4 + (wid & 1) * 2 + c;
        async_cp16(K + (size_t)(win * 8 + srow) * 512 + kn + scol,
                   dst + win * 512);
    }
}

// ---------------------------------------------------------------------------
// Pass 1 v3 (r18 = r17 resubmit; round-2 failure was container infra, not the
// kernel -- barrier/vmcnt structure identical to the r16 kernel that passed).
// 256x256 tile, 8 waves (2Mx4N), BK=64, 128 KiB LDS dbuf, 8-phase
// counted-vmcnt schedule (T3+T4) + setprio (T5), GRAY-CODE phase order
// (0,0)->(0,1)->(1,1)->(1,0) with register-held operands: both B-halves
// loaded once per kt (bf0/bf1, 8 ds_read_b128), A-half loaded on ih change
// (8 reads). 24 reads/kt/wave vs r16's 48 -- r16 post-mortem: LDS read pipe
// (96 b128/CU/phase = 384-1150 cyc vs 160 cyc MFMA/SIMD) was the critical
// path that lgkmcnt(0) serialized on (MfmaUtil 24.5%, VALU 29%, both pipes
// idle ~25us of 55). Staging + vmcnt ledger unchanged: half-tiles of kt+1 at
// A0,B0@p0, B1@p1, A1@p2; waits vmcnt(6)@p1, vmcnt(2)@p3 (never 0 in loop).
// Pbuf layout [i][tid][rg] -> dwordx4 stores here, dwordx4 loads in colsum.
// Grid (16, 16, 2), 512 threads.
// ---------------------------------------------------------------------------
__global__ __launch_bounds__(512, 2) void attn_pass1p(
    const u16* __restrict__ Qb, const u16* __restrict__ Kb,
    float2* __restrict__ statsP, u32* __restrict__ Pbuf) {
    __shared__ __align__(16) u16 As[2][16384];
    __shared__ __align__(16) u16 Bs[2][16384];
    int tid = threadIdx.x;
    int mblk = blockIdx.x, nblk = blockIdx.y, b = blockIdx.z;
    const u16* Q = Qb + ((size_t)(b * 4096 + mblk * 256)) * 512;
    const u16* K = Kb + ((size_t)(b * 4096 + nblk * 256)) * 512;
    int lane = tid & 63, wid = tid >> 6;
    int quad = lane >> 4, l15 = lane & 15;
    int wm = wid >> 2, wn = wid & 3;
    int Gw = lane ^ ((lane >> 3) & 7);
    int srow = Gw >> 3, scol = (Gw & 7) * 8;
    int rl = l15 & 7, winl = l15 >> 3;
    int Pr[2];
#pragma unroll
    for (int h = 0; h < 2; h++)
        Pr[h] = (rl * 8 + ((quad + h * 4) ^ rl)) * 8;

    f32x4 acc[8][4];
#pragma unroll
    for (int i = 0; i < 8; i++)
#pragma unroll
        for (int j = 0; j < 4; j++) acc[i][j] = (f32x4){0.f, 0.f, 0.f, 0.f};

    // Prologue: stage tile 0 fully, single full drain (only one in kernel).
    stage_half_A(Q, &As[0][0], 0, 0, wid, srow, scol);
    stage_half_B(K, &Bs[0][0], 0, 0, wid, srow, scol);
    stage_half_B(K, &Bs[0][0], 0, 1, wid, srow, scol);
    stage_half_A(Q, &As[0][0], 0, 1, wid, srow, scol);
    asm volatile("s_waitcnt vmcnt(0)" ::: "memory");
    __builtin_amdgcn_s_barrier();
    asm volatile("" ::: "memory");

    for (int kt = 0; kt < 8; ++kt) {
        const u16* Ac = &As[kt & 1][0];
        const u16* Bc = &Bs[kt & 1][0];
        u16* An = &As[(kt + 1) & 1][0];
        u16* Bn = &Bs[(kt + 1) & 1][0];
        int kn = (kt + 1) * 64;
        bool pf = (kt < 7);
        short8 af[4][2], bf0[2][2], bf1[2][2];
#pragma unroll
        for (int ph = 0; ph < 4; ++ph) {
            // Gray code: (ih,jh) = (0,0),(0,1),(1,1),(1,0)
            const int ih = ph >> 1;
            const int jh = (ph ^ (ph >> 1)) & 1;
            if (ph == 0) {
#pragma unroll
                for (int h = 0; h < 2; h++)
#pragma unroll
                    for (int ii = 0; ii < 4; ii++)
                        af[ii][h] = mfma_ld(
                            Ac, (wm * 16 + ii * 2 + winl) * 512 + Pr[h]);
#pragma unroll
                for (int h = 0; h < 2; h++)
#pragma unroll
                    for (int jj = 0; jj < 2; jj++)
                        bf0[jj][h] = mfma_ld(
                            Bc, (wn * 8 + jj * 2 + winl) * 512 + Pr[h]);
            } else if (ph == 1) {
#pragma unroll
                for (int h = 0; h < 2; h++)
#pragma unroll
                    for (int jj = 0; jj < 2; jj++)
                        bf1[jj][h] = mfma_ld(
                            Bc, (wn * 8 + 4 + jj * 2 + winl) * 512 + Pr[h]);
            } else if (ph == 2) {
#pragma unroll
                for (int h = 0; h < 2; h++)
#pragma unroll
                    for (int ii = 0; ii < 4; ii++)
                        af[ii][h] = mfma_ld(
                            Ac, (wm * 16 + 8 + ii * 2 + winl) * 512 + Pr[h]);
            }
            if (pf) {
                if (ph == 0) {
                    stage_half_A(Q, An, kn, 0, wid, srow, scol);
                    stage_half_B(K, Bn, kn, 0, wid, srow, scol);
                } else if (ph == 1) {
                    stage_half_B(K, Bn, kn, 1, wid, srow, scol);
                } else if (ph == 2) {
                    stage_half_A(Q, An, kn, 1, wid, srow, scol);
                }
            }
            if (ph == 1) {
                if (pf) asm volatile("s_waitcnt vmcnt(6)" ::: "memory");
                else    asm volatile("s_waitcnt vmcnt(0)" ::: "memory");
            }
            if (ph == 3) asm volatile("s_waitcnt vmcnt(2)" ::: "memory");
            asm volatile("" ::: "memory");
            __builtin_amdgcn_s_barrier();
            asm volatile("s_waitcnt lgkmcnt(0)" ::: "memory");
            __builtin_amdgcn_s_setprio(1);
            if (jh == 0) {
#pragma unroll
                for (int h = 0; h < 2; h++)
#pragma unroll
                    for (int ii = 0; ii < 4; ii++)
#pragma unroll
                        for (int jj = 0; jj < 2; jj++)
                            acc[ih * 4 + ii][jj] =
                                __builtin_amdgcn_mfma_f32_16x16x32_bf16(
                                    af[ii][h], bf0[jj][h],
                                    acc[ih * 4 + ii][jj], 0, 0, 0);
            } else {
#pragma unroll
                for (int h = 0; h < 2; h++)
#pragma unroll
                    for (int ii = 0; ii < 4; ii++)
#pragma unroll
                        for (int jj = 0; jj < 2; jj++)
                            acc[ih * 4 + ii][2 + jj] =
                                __builtin_amdgcn_mfma_f32_16x16x32_bf16(
                                    af[ii][h], bf1[jj][h],
                                    acc[ih * 4 + ii][2 + jj], 0, 0, 0);
            }
            __builtin_amdgcn_s_setprio(0);
            asm volatile("" ::: "memory");
            __builtin_amdgcn_s_barrier();
            asm volatile("" ::: "memory");
        }
    }

    // Epilogue: per (i,rg) row, chunk-max over the 64 cols (4 j-frags x 16
    // l15 lanes), P in fp8, stats write. No LDS use -> no barrier needed.
    // Pbuf layout [i][tid][rg]: one dwordx4 store per i.
    u32* Pt = Pbuf + ((size_t)((b * 16 + mblk) * 16 + nblk)) * 16384;
    int ch = nblk * 4 + wn;
    float2* Sp = statsP + ((size_t)(b * 64 + ch)) * 4096;
    int mbase = mblk * 256 + wm * 128;
#pragma unroll
    for (int i = 0; i < 8; i++) {
        u32x4 pk;
#pragma unroll
        for (int rg = 0; rg < 4; rg++) {
            float v0 = acc[i][0][rg], v1 = acc[i][1][rg];
            float v2 = acc[i][2][rg], v3 = acc[i][3][rg];
            float Mt = fmaxf(fmaxf(v0, v1), fmaxf(v2, v3));
            Mt = dpp_max16(Mt);  // uniform over the 16 l15 lanes
            float e8 = Mt - 8.0f;  // x256 pre-scale for fp8 range
            float p0 = fexp2(v0 - e8), p1 = fexp2(v1 - e8);
            float p2 = fexp2(v2 - e8), p3 = fexp2(v3 - e8);
            pk[rg] = fp8x4_pack(p0, p1, p2, p3);
            float L = dpp_sum16(p0 + p1 + p2 + p3);
            if (l15 == 0)
                Sp[mbase + i * 16 + quad * 4 + rg] =
                    make_float2(Mt, L * 0.00390625f);  // true L_ch
        }
        *(u32x4*)&Pt[i * 2048 + tid * 4] = pk;
    }
}

// ---------------------------------------------------------------------------
// c = M + log2(Z) per row. Separate kernel (r10: fusing into colsum = 64x
// redundancy, +10us; r7: retained-array version spilled). grid 32 x 256.
// ---------------------------------------------------------------------------
__global__ void reduce_stats2(const float2* __restrict__ statsP,
                              float* __restrict__ cstat) {
    int t = blockIdx.x * 256 + threadIdx.x;
    int b = t >> 12, m = t & 4095;
    const float2* sp = statsP + (size_t)b * 64 * 4096 + m;
    float M = -INFINITY;
#pragma unroll 4
    for (int ch = 0; ch < 64; ch++) M = fmaxf(M, sp[(size_t)ch * 4096].x);
    float Z = 0.f;
#pragma unroll 4
    for (int ch = 0; ch < 64; ch++) {
        float2 p = sp[(size_t)ch * 4096];
        Z += p.y * fexp2(p.x - M);
    }
    cstat[t] = M + __log2f(Z);
}

// ---------------------------------------------------------------------------
// Weighted column sums v3 (Pbuf layout [i][tid][rg] -> dwordx4 loads):
// S[n] += sum_m P_fp8[m,n] * exp2(Mt[m]-8-c[m]). F-SKIP (2^-58): dropped
// mass/col <= 4096*256*2^-58 = 2^-38, scale err <= 3.6e-3.
// grid (nblk=16, mgrp=8 (2 mblks each), b=2), 512 threads: thread tid holds
// the SAME (m,n) cells it wrote in pass 1.
// ---------------------------------------------------------------------------
__global__ __launch_bounds__(512) void colsum(
    const u32* __restrict__ Pbuf, const float2* __restrict__ statsP,
    const float* __restrict__ cstat, float* __restrict__ Sg) {
    int tid = threadIdx.x, lane = tid & 63, wid = tid >> 6;
    int quad = lane >> 4, l15 = lane & 15;
    int wm = wid >> 2, wn = wid & 3;
    int nblk = blockIdx.x, mgrp = blockIdx.y, b = blockIdx.z;
    int ch = nblk * 4 + wn;
    const float2* Sp = statsP + ((size_t)(b * 64 + ch)) * 4096;
    const float* Cp = cstat + (size_t)b * 4096;
    float cp[4] = {0.f, 0.f, 0.f, 0.f};
    for (int mb = 0; mb < 2; mb++) {
        int mblk = mgrp * 2 + mb;
        const u32* Pt =
            Pbuf + ((size_t)((b * 16 + mblk) * 16 + nblk)) * 16384;
#pragma unroll
        for (int i = 0; i < 8; i++) {
            int r0 = mblk * 256 + wm * 128 + i * 16 + quad * 4;
            float4 s01 = *(const float4*)&Sp[r0];      // (M0,L0,M1,L1)
            float4 s23 = *(const float4*)&Sp[r0 + 2];  // (M2,L2,M3,L3)
            float4 cv = *(const float4*)&Cp[r0];
            float fv[4] = {fexp2(s01.x - 8.0f - cv.x),
                           fexp2(s01.z - 8.0f - cv.y),
                           fexp2(s23.x - 8.0f - cv.z),
                           fexp2(s23.z - 8.0f - cv.w)};
            float fm = fmaxf(fmaxf(fv[0], fv[1]), fmaxf(fv[2], fv[3]));
            if (fm > 3.469446951953614e-18f) {  // 2^-58: see header comment
                u32x4 e4 = *(const u32x4*)&Pt[i * 2048 + tid * 4];
#pragma unroll
                for (int rg = 0; rg < 4; rg++) {
                    u32 e = e4[rg];
                    cp[0] += FP8_DEC(e, 0) * fv[rg];
                    cp[1] += FP8_DEC(e, 1) * fv[rg];
                    cp[2] += FP8_DEC(e, 2) * fv[rg];
                    cp[3] += FP8_DEC(e, 3) * fv[rg];
                }
            }
        }
    }
#pragma unroll
    for (int j = 0; j < 4; j++) {
        float s = cp[j];
        s += __shfl_xor(s, 16);
        s += __shfl_xor(s, 32);
        if (lane < 16)
            atomicAdd(&Sg[b * 4096 + nblk * 256 + wn * 64 + j * 16 + l15], s);
    }
}

// ---------------------------------------------------------------------------
// Final: out = relu(BN((V*rowscale) . Wo^T + bo)) + X  (fp32 out)
// 64x128 tiles, grid (128, 4). m0 in [0,8192) == flat (b,m).
// ---------------------------------------------------------------------------
__global__ __launch_bounds__(256) void gemm_final(
    const u16* __restrict__ A, const u16* __restrict__ Bt,
    const float* __restrict__ Sg, const float* __restrict__ bo,
    const float* __restrict__ g, const float* __restrict__ bb,
    const float* __restrict__ mean, const float* __restrict__ var,
    const float* __restrict__ X, float* __restrict__ out) {
    __shared__ __align__(16) u16 As[4096];
    __shared__ __align__(16) u16 Bs[8192];
    int tid = threadIdx.x;
    int m0 = blockIdx.x * 64, n0 = blockIdx.y * 128;
    f32x4 acc[2][4];
#pragma unroll
    for (int i = 0; i < 2; i++)
#pragma unroll
        for (int j = 0; j < 4; j++) acc[i][j] = (f32x4){0.f, 0.f, 0.f, 0.f};
    gemm512_r64(A + (size_t)m0 * 512, Bt + (size_t)n0 * 512, As, Bs, acc, tid);
    int lane = tid & 63, quad = lane >> 4, l15 = lane & 15;
    int wm = tid >> 7, wn = (tid >> 6) & 1;
    float sc[2][4];
#pragma unroll
    for (int i = 0; i < 2; i++) {
        float4 s = *(const float4*)&Sg[m0 + wm * 32 + i * 16 + quad * 4];
        float v[4] = {s.x, s.y, s.z, s.w};
#pragma unroll
        for (int rg = 0; rg < 4; rg++) sc[i][rg] = v[rg] / (1e-9f + v[rg]);
    }
#pragma unroll
    for (int j = 0; j < 4; j++) {
        int n = n0 + wn * 64 + j * 16 + l15;
        float aj = rsqrtf(var[n] + 1e-5f) * g[n];
        float cj = bb[n] - mean[n] * aj;
        float bj = bo[n];
#pragma unroll
        for (int i = 0; i < 2; i++)
#pragma unroll
            for (int rg = 0; rg < 4; rg++) {
                int m = m0 + wm * 32 + i * 16 + quad * 4 + rg;
                float x = acc[i][j][rg] * sc[i][rg] + bj;
                float y = x * aj + cj;
                out[(size_t)m * 512 + n] = fmaxf(y, 0.f) + X[(size_t)m * 512 + n];
            }
    }
}

// ---------------------------------------------------------------------------
extern "C" void kernel_launch(void* const* d_in, const int* in_sizes, int n_in,
                              void* d_out, int out_size, void* d_ws, size_t ws_size,
                              hipStream_t stream) {
    const float* X  = (const float*)d_in[0];
    const float* Wq = (const float*)d_in[1];
    const float* Wk = (const float*)d_in[2];
    const float* Wv = (const float*)d_in[3];
    const float* Wo = (const float*)d_in[4];
    const float* bq = (const float*)d_in[5];
    const float* bk = (const float*)d_in[6];
    const float* bv = (const float*)d_in[7];
    const float* bo = (const float*)d_in[8];
    const float* g    = (const float*)d_in[9];
    const float* bb   = (const float*)d_in[10];
    const float* mean = (const float*)d_in[11];
    const float* var  = (const float*)d_in[12];
    float* out = (float*)d_out;

    char* ws = (char*)d_ws;
    u16* Xb  = (u16*)(ws + 0);                    // 8 MB
    u16* Wqt = (u16*)(ws + 8388608);              // 4x512KB (Wq,Wk,Wv,Wo)
    u16* Wot = (u16*)(ws + 9961472);
    u16* Qb  = (u16*)(ws + 10485760);             // Q,K,V contiguous 3x8MB
    u16* Kb  = (u16*)(ws + 18874368);
    u16* Vb  = (u16*)(ws + 27262976);
    float2* statsP = (float2*)(ws + 35651584);    // [b][64][4096] f2 = 4 MB
    float* Sg      = (float*)(ws + 39845888);     // 32 KB
    float* cstat   = (float*)(ws + 39878656);     // 32 KB
    u32* Pbuf      = (u32*)(ws + 39911424);       // 32 MB fp8 P

    prep<<<5121, 256, 0, stream>>>(X, Wq, Wk, Wv, Wo, Xb, Wqt, Wqt + 262144,
                                   Wqt + 524288, Wot, Sg);
    gemm_qkv<<<dim3(64, 4, 3), 256, 0, stream>>>(Xb, Wqt, bq, bk, bv, Qb);
    attn_pass1p<<<dim3(16, 16, 2), 512, 0, stream>>>(Qb, Kb, statsP, Pbuf);
    reduce_stats2<<<32, 256, 0, stream>>>(statsP, cstat);
    colsum<<<dim3(16, 8, 2), 512, 0, stream>>>(Pbuf, statsP, cstat, Sg);
    gemm_final<<<dim3(128, 4), 256, 0, stream>>>(Vb, Wot, Sg, bo, g, bb, mean, var,
                                                 X, out);
}

// Round 4
// 202.342 us; speedup vs baseline: 1.0149x; 1.0077x over previous
//
#include <hip/hip_runtime.h>
#include <hip/hip_bf16.h>

typedef unsigned short u16;
typedef unsigned int u32;
typedef __attribute__((ext_vector_type(8))) short short8;
typedef __attribute__((ext_vector_type(4))) float f32x4;
typedef __attribute__((ext_vector_type(4))) unsigned int u32x4;

__device__ __forceinline__ u16 f2bf(float f) {
    union { float f; unsigned u; } v; v.f = f;
    unsigned r = v.u + 0x7fffu + ((v.u >> 16) & 1u);
    return (u16)(r >> 16);
}

__device__ __forceinline__ float fexp2(float x) {
#if __has_builtin(__builtin_amdgcn_exp2f)
    return __builtin_amdgcn_exp2f(x);
#else
    return __expf(x * 0.6931471805599453f);
#endif
}

// ---------------------------------------------------------------------------
// DPP 16-lane butterfly (r15): __shfl_xor lowers to ds_swizzle (~5.8 cyc DS);
// DPP row ops fuse into the max/add as ONE full-rate VALU op. Masks
// {1,2,7,15} (quad_perm[1,0,3,2]=0xB1, quad_perm[2,3,0,1]=0x4E,
// row_half_mirror=0x141, row_mirror=0x140) are GF(2)-independent -> valid
// butterfly over each contiguous 16-lane row (= our quad*16+l15 groups).
// ---------------------------------------------------------------------------
template <int CTRL>
__device__ __forceinline__ float fdpp(float x) {
    int xi = __builtin_bit_cast(int, x);
    int r = __builtin_amdgcn_update_dpp(0, xi, CTRL, 0xF, 0xF, true);
    return __builtin_bit_cast(float, r);
}
__device__ __forceinline__ float dpp_max16(float m) {
    m = fmaxf(m, fdpp<0xB1>(m));   // xor 1
    m = fmaxf(m, fdpp<0x4E>(m));   // xor 2
    m = fmaxf(m, fdpp<0x141>(m));  // xor 7 (row_half_mirror)
    m = fmaxf(m, fdpp<0x140>(m));  // xor 15 (row_mirror)
    return m;
}
__device__ __forceinline__ float dpp_sum16(float s) {
    s += fdpp<0xB1>(s);
    s += fdpp<0x4E>(s);
    s += fdpp<0x141>(s);
    s += fdpp<0x140>(s);
    return s;
}

// ---------------------------------------------------------------------------
// fp8 e4m3 pack/unpack (P pre-scaled x256; r9-r13 absmax 0.078).
// ---------------------------------------------------------------------------
#if __has_builtin(__builtin_amdgcn_cvt_pk_fp8_f32) && \
    __has_builtin(__builtin_amdgcn_cvt_f32_fp8)
#define FP8_HW 1
#else
#define FP8_HW 0
#endif

#if !FP8_HW
__device__ __forceinline__ u32 sw_fp8(float x) {  // x in [0, 448]
    union { float f; u32 u; } v; v.f = x;
    int E = (int)(v.u >> 23) - 127;
    if (x < 0.001953125f) return 0;
    if (E < -6) return (u32)(x * 512.0f + 0.5f);
    u32 m = v.u & 0x7fffffu;
    u32 r = (m + 0x80000u) >> 20;
    u32 bits = ((u32)(E + 7) << 3) + r;
    return bits > 0x7eu ? 0x7eu : bits;
}
__device__ __forceinline__ float sw_fp8d(u32 b) {
    u32 e = (b >> 3) & 15u, m = b & 7u;
    if (e == 0) return (float)m * 0.001953125f;
    union { u32 u; float f; } v; v.u = ((e + 120u) << 23) | (m << 20);
    return v.f;
}
#endif

__device__ __forceinline__ u32 fp8x4_pack(float p0, float p1, float p2, float p3) {
#if FP8_HW
    u32 v = (u32)__builtin_amdgcn_cvt_pk_fp8_f32(p0, p1, 0, false);
    v = (u32)__builtin_amdgcn_cvt_pk_fp8_f32(p2, p3, (int)v, true);
    return v;
#else
    return sw_fp8(p0) | (sw_fp8(p1) << 8) | (sw_fp8(p2) << 16) | (sw_fp8(p3) << 24);
#endif
}

#if FP8_HW
#define FP8_DEC(v, s) __builtin_amdgcn_cvt_f32_fp8((int)(v), (s))
#else
#define FP8_DEC(v, s) sw_fp8d(((v) >> ((s) * 8)) & 0xffu)
#endif

// async 16B global->LDS DMA (m97 pattern).
__device__ __forceinline__ void async_cp16(const u16* g, u16* l) {
    __builtin_amdgcn_global_load_lds(
        (const __attribute__((address_space(1))) void*)g,
        (__attribute__((address_space(3))) void*)l, 16, 0, 0);
}

// ---------------------------------------------------------------------------
// XOR-swizzled LDS GEMM cores, BK=64 (r13; zero SQ_LDS_BANK_CONFLICT).
// ---------------------------------------------------------------------------
__device__ __forceinline__ short8 mfma_ld(const u16* base, int off) {
    return *(const short8*)&base[off];
}

// 128x128x512: A [128,512] bf16 rm, B^T [128,512] bf16 rm (computes A.B^T).
__device__ __forceinline__ void gemm512(const u16* __restrict__ A,
                                        const u16* __restrict__ B,
                                        u16* As, u16* Bs,
                                        f32x4 acc[4][4], int tid) {
    const int lane = tid & 63, w = tid >> 6;
    const int quad = lane >> 4, l15 = lane & 15;
    const int wm = tid >> 7, wn = (tid >> 6) & 1;
    const int Gw = lane ^ ((lane >> 3) & 7);
    const int srow = Gw >> 3;
    const int scol = (Gw & 7) * 8;
    const int rl = l15 & 7;
    const int winl = l15 >> 3;
    int Pr[2];
#pragma unroll
    for (int h = 0; h < 2; h++)
        Pr[h] = (rl * 8 + ((quad + h * 4) ^ rl)) * 8;
    const int winA0 = (wm * 64) >> 3, winB0 = (wn * 64) >> 3;
    for (int k0 = 0; k0 < 512; k0 += 64) {
        __syncthreads();
#pragma unroll
        for (int t = 0; t < 4; t++) {
            int win = w * 4 + t;
            async_cp16(A + (size_t)(win * 8 + srow) * 512 + k0 + scol,
                       As + win * 512);
            async_cp16(B + (size_t)(win * 8 + srow) * 512 + k0 + scol,
                       Bs + win * 512);
        }
        __syncthreads();
#pragma unroll
        for (int h = 0; h < 2; h++) {
            short8 af[4], bfr[4];
#pragma unroll
            for (int i = 0; i < 4; i++)
                af[i] = mfma_ld(As, (winA0 + i * 2 + winl) * 512 + Pr[h]);
#pragma unroll
            for (int j = 0; j < 4; j++)
                bfr[j] = mfma_ld(Bs, (winB0 + j * 2 + winl) * 512 + Pr[h]);
#pragma unroll
            for (int i = 0; i < 4; i++)
#pragma unroll
                for (int j = 0; j < 4; j++)
                    acc[i][j] = __builtin_amdgcn_mfma_f32_16x16x32_bf16(
                        af[i], bfr[j], acc[i][j], 0, 0, 0);
        }
    }
}

// 64x128x512 variant (A 64 rows). As: 4096 u16, Bs: 8192 u16.
__device__ __forceinline__ void gemm512_r64(const u16* __restrict__ A,
                                            const u16* __restrict__ B,
                                            u16* As, u16* Bs,
                                            f32x4 acc[2][4], int tid) {
    const int lane = tid & 63, w = tid >> 6;
    const int quad = lane >> 4, l15 = lane & 15;
    const int wm = tid >> 7, wn = (tid >> 6) & 1;
    const int Gw = lane ^ ((lane >> 3) & 7);
    const int srow = Gw >> 3;
    const int scol = (Gw & 7) * 8;
    const int rl = l15 & 7;
    const int winl = l15 >> 3;
    int Pr[2];
#pragma unroll
    for (int h = 0; h < 2; h++)
        Pr[h] = (rl * 8 + ((quad + h * 4) ^ rl)) * 8;
    const int winA0 = (wm * 32) >> 3, winB0 = (wn * 64) >> 3;
    for (int k0 = 0; k0 < 512; k0 += 64) {
        __syncthreads();
#pragma unroll
        for (int t = 0; t < 2; t++) {
            int win = w * 2 + t;
            async_cp16(A + (size_t)(win * 8 + srow) * 512 + k0 + scol,
                       As + win * 512);
        }
#pragma unroll
        for (int t = 0; t < 4; t++) {
            int win = w * 4 + t;
            async_cp16(B + (size_t)(win * 8 + srow) * 512 + k0 + scol,
                       Bs + win * 512);
        }
        __syncthreads();
#pragma unroll
        for (int h = 0; h < 2; h++) {
            short8 af[2], bfr[4];
#pragma unroll
            for (int i = 0; i < 2; i++)
                af[i] = mfma_ld(As, (winA0 + i * 2 + winl) * 512 + Pr[h]);
#pragma unroll
            for (int j = 0; j < 4; j++)
                bfr[j] = mfma_ld(Bs, (winB0 + j * 2 + winl) * 512 + Pr[h]);
#pragma unroll
            for (int i = 0; i < 2; i++)
#pragma unroll
                for (int j = 0; j < 4; j++)
                    acc[i][j] = __builtin_amdgcn_mfma_f32_16x16x32_bf16(
                        af[i], bfr[j], acc[i][j], 0, 0, 0);
        }
    }
}

// ---------------------------------------------------------------------------
// Fused prep: [0,4096) convert X->bf16; [4096,5120) transpose weights;
// 5120: zero Sg (per-launch, graph-safe).
// ---------------------------------------------------------------------------
__global__ void prep(const float* __restrict__ X, const float* __restrict__ W0,
                     const float* __restrict__ W1, const float* __restrict__ W2,
                     const float* __restrict__ W3, u16* __restrict__ Xb,
                     u16* __restrict__ T0, u16* __restrict__ T1,
                     u16* __restrict__ T2, u16* __restrict__ T3,
                     float* __restrict__ Sg) {
    __shared__ float tile[32][33];
    int id = blockIdx.x, tid = threadIdx.x;
    if (id == 5120) {
        float4 z = {0.f, 0.f, 0.f, 0.f};
#pragma unroll
        for (int t = 0; t < 8; t++) ((float4*)Sg)[tid + t * 256] = z;
        return;
    }
    if (id < 4096) {
        int idx = (id * 256 + tid) * 4;
        float4 v = *(const float4*)&X[idx];
        ushort4 o;
        o.x = f2bf(v.x); o.y = f2bf(v.y); o.z = f2bf(v.z); o.w = f2bf(v.w);
        *(ushort4*)&Xb[idx] = o;
        return;
    }
    int t = id - 4096;
    int z = t >> 8, rem = t & 255;
    int bo_ = (rem & 15) * 32, bi = (rem >> 4) * 32;
    const float* src; u16* dst;
    switch (z) {
        case 0: src = W0; dst = T0; break;
        case 1: src = W1; dst = T1; break;
        case 2: src = W2; dst = T2; break;
        default: src = W3; dst = T3; break;
    }
    int tx = tid & 31, ty = tid >> 5;
#pragma unroll
    for (int s = 0; s < 4; s++) {
        int i = bi + ty + s * 8;
        tile[ty + s * 8][tx] = src[i * 512 + bo_ + tx];
    }
    __syncthreads();
#pragma unroll
    for (int s = 0; s < 4; s++) {
        int o = bo_ + ty + s * 8;
        dst[o * 512 + bi + tx] = f2bf(tile[tx][ty + s * 8]);
    }
}

// ---------------------------------------------------------------------------
// Fused QKV projection. z==0 (Q) scaled by log2(e) -> base-2 score domain.
// ---------------------------------------------------------------------------
__global__ __launch_bounds__(256) void gemm_qkv(
    const u16* __restrict__ Xb, const u16* __restrict__ Wall,
    const float* __restrict__ bq, const float* __restrict__ bk,
    const float* __restrict__ bv, u16* __restrict__ Qall) {
    __shared__ __align__(16) u16 As[8192];
    __shared__ __align__(16) u16 Bs[8192];
    int tid = threadIdx.x;
    int m0 = blockIdx.x * 128, n0 = blockIdx.y * 128, z = blockIdx.z;
    const u16* Bt = Wall + (size_t)z * 262144 + (size_t)n0 * 512;
    const float* bias = (z == 0) ? bq : (z == 1) ? bk : bv;
    const float qs = (z == 0) ? 1.44269504088896340736f : 1.0f;
    u16* C = Qall + (size_t)z * 4194304;
    f32x4 acc[4][4];
#pragma unroll
    for (int i = 0; i < 4; i++)
#pragma unroll
        for (int j = 0; j < 4; j++) acc[i][j] = (f32x4){0.f, 0.f, 0.f, 0.f};
    gemm512(Xb + (size_t)m0 * 512, Bt, As, Bs, acc, tid);
    int lane = tid & 63, quad = lane >> 4, l15 = lane & 15;
    int wm = tid >> 7, wn = (tid >> 6) & 1;
#pragma unroll
    for (int j = 0; j < 4; j++) {
        int n = n0 + wn * 64 + j * 16 + l15;
        float bvv = bias[n];
#pragma unroll
        for (int i = 0; i < 4; i++)
#pragma unroll
            for (int rg = 0; rg < 4; rg++) {
                int m = m0 + wm * 64 + i * 16 + quad * 4 + rg;
                C[(size_t)m * 512 + n] = f2bf((acc[i][j][rg] + bvv) * qs);
            }
    }
}

// ---------------------------------------------------------------------------
// Staging helpers for the 8-phase 256x256 attention pass-1 (T3+T4 schedule).
// Half-tiles: A-half(ih) = wins wm'*16 + ih*8 + [0,8); B-half(jh) = wins
// wn'*8 + jh*4 + [0,4). Each wave stages 2 wins (1 KiB each) per half.
// LDS dest is wave-uniform base + lane*16 (global_load_lds constraint);
// the XOR swizzle lives in the per-lane GLOBAL source address (m173 pattern).
// ---------------------------------------------------------------------------
__device__ __forceinline__ void stage_half_A(const u16* __restrict__ Q,
                                             u16* dst, int kn, int half,
                                             int wid, int srow, int scol) {
#pragma unroll
    for (int c = 0; c < 2; c++) {
        int win = (wid >> 2) * 16 + half * 8 + (wid & 3) * 2 + c;
        async_cp16(Q + (size_t)(win * 8 + srow) * 512 + kn + scol,
                   dst + win * 512);
    }
}
__device__ __forceinline__ void stage_half_B(const u16* __restrict__ K,
                                             u16* dst, int kn, int half,
                                             int wid, int srow, int scol) {
#pragma unroll
    for (int c = 0; c < 2; c++) {
        int win = (wid >> 1) * 8 + half * 4 + (wid & 1) * 2 + c;
        async_cp16(K + (size_t)(win * 8 + srow) * 512 + kn + scol,
                   dst + win * 512);
    }
}

// ---------------------------------------------------------------------------
// Pass 1 v4 (r19): SINGLE barrier per phase. r17 post-mortem: with the
// post-MFMA barrier, all 8 waves run in lockstep -> per kt the LDS-read time
// (~2300 cyc/CU) and MFMA time (~2048 cyc/CU) ADD (lgkmcnt(0) serializes
// within a phase, barrier serializes across waves); MfmaUtil capped at ~25%
// = 12.6us busy == the 13.8us roofline of 34.4 GFLOP, i.e. the pipe is
// perfect when on, idle 75%. Dropping the post-MFMA barrier lets waves skew
// one phase: one wave's ds_reads overlap the other's MFMA -> kt time ->
// max(LDS, MFMA). Hazard ledger for 1-barrier/phase (all verified):
//  - next-phase ds_reads on current buffer vs MFMA reads: read-after-read OK
//  - staging writes target the other dbuf half within a kt: OK
//  - kt boundary (kt+1 ph0 stages into the buffer kt read): gray-code ph3
//    has ZERO ds_reads; every wave's reads of the old buffer retired at its
//    own ph2 lgkmcnt(0) BEFORE the ph3-entry barrier -> any wave past
//    ph3-entry implies no future reads of the old buffer by anyone.
//  - cross-wave staging visibility: each wave's vmcnt wait precedes the
//    phase-entry barrier (ph1 wait(6) publishes old A1n before ph2 reads;
//    ph3 wait(2) publishes A0n/B0n/B1n before kt+1 ph0 reads). Never 0 in
//    the main loop. Grid (16, 16, 2), 512 threads.
// ---------------------------------------------------------------------------
__global__ __launch_bounds__(512, 2) void attn_pass1p(
    const u16* __restrict__ Qb, const u16* __restrict__ Kb,
    float2* __restrict__ statsP, u32* __restrict__ Pbuf) {
    __shared__ __align__(16) u16 As[2][16384];
    __shared__ __align__(16) u16 Bs[2][16384];
    int tid = threadIdx.x;
    int mblk = blockIdx.x, nblk = blockIdx.y, b = blockIdx.z;
    const u16* Q = Qb + ((size_t)(b * 4096 + mblk * 256)) * 512;
    const u16* K = Kb + ((size_t)(b * 4096 + nblk * 256)) * 512;
    int lane = tid & 63, wid = tid >> 6;
    int quad = lane >> 4, l15 = lane & 15;
    int wm = wid >> 2, wn = wid & 3;
    int Gw = lane ^ ((lane >> 3) & 7);
    int srow = Gw >> 3, scol = (Gw & 7) * 8;
    int rl = l15 & 7, winl = l15 >> 3;
    int Pr[2];
#pragma unroll
    for (int h = 0; h < 2; h++)
        Pr[h] = (rl * 8 + ((quad + h * 4) ^ rl)) * 8;

    f32x4 acc[8][4];
#pragma unroll
    for (int i = 0; i < 8; i++)
#pragma unroll
        for (int j = 0; j < 4; j++) acc[i][j] = (f32x4){0.f, 0.f, 0.f, 0.f};

    // Prologue: stage tile 0 fully, single full drain (only one in kernel).
    stage_half_A(Q, &As[0][0], 0, 0, wid, srow, scol);
    stage_half_B(K, &Bs[0][0], 0, 0, wid, srow, scol);
    stage_half_B(K, &Bs[0][0], 0, 1, wid, srow, scol);
    stage_half_A(Q, &As[0][0], 0, 1, wid, srow, scol);
    asm volatile("s_waitcnt vmcnt(0)" ::: "memory");
    __builtin_amdgcn_s_barrier();
    asm volatile("" ::: "memory");

    for (int kt = 0; kt < 8; ++kt) {
        const u16* Ac = &As[kt & 1][0];
        const u16* Bc = &Bs[kt & 1][0];
        u16* An = &As[(kt + 1) & 1][0];
        u16* Bn = &Bs[(kt + 1) & 1][0];
        int kn = (kt + 1) * 64;
        bool pf = (kt < 7);
        short8 af[4][2], bf0[2][2], bf1[2][2];
#pragma unroll
        for (int ph = 0; ph < 4; ++ph) {
            // Gray code: (ih,jh) = (0,0),(0,1),(1,1),(1,0)
            const int ih = ph >> 1;
            const int jh = (ph ^ (ph >> 1)) & 1;
            if (ph == 0) {
#pragma unroll
                for (int h = 0; h < 2; h++)
#pragma unroll
                    for (int ii = 0; ii < 4; ii++)
                        af[ii][h] = mfma_ld(
                            Ac, (wm * 16 + ii * 2 + winl) * 512 + Pr[h]);
#pragma unroll
                for (int h = 0; h < 2; h++)
#pragma unroll
                    for (int jj = 0; jj < 2; jj++)
                        bf0[jj][h] = mfma_ld(
                            Bc, (wn * 8 + jj * 2 + winl) * 512 + Pr[h]);
            } else if (ph == 1) {
#pragma unroll
                for (int h = 0; h < 2; h++)
#pragma unroll
                    for (int jj = 0; jj < 2; jj++)
                        bf1[jj][h] = mfma_ld(
                            Bc, (wn * 8 + 4 + jj * 2 + winl) * 512 + Pr[h]);
            } else if (ph == 2) {
#pragma unroll
                for (int h = 0; h < 2; h++)
#pragma unroll
                    for (int ii = 0; ii < 4; ii++)
                        af[ii][h] = mfma_ld(
                            Ac, (wm * 16 + 8 + ii * 2 + winl) * 512 + Pr[h]);
            }
            if (pf) {
                if (ph == 0) {
                    stage_half_A(Q, An, kn, 0, wid, srow, scol);
                    stage_half_B(K, Bn, kn, 0, wid, srow, scol);
                } else if (ph == 1) {
                    stage_half_B(K, Bn, kn, 1, wid, srow, scol);
                } else if (ph == 2) {
                    stage_half_A(Q, An, kn, 1, wid, srow, scol);
                }
            }
            if (ph == 1) {
                if (pf) asm volatile("s_waitcnt vmcnt(6)" ::: "memory");
                else    asm volatile("s_waitcnt vmcnt(0)" ::: "memory");
            }
            if (ph == 3) asm volatile("s_waitcnt vmcnt(2)" ::: "memory");
            asm volatile("" ::: "memory");
            __builtin_amdgcn_s_barrier();
            asm volatile("s_waitcnt lgkmcnt(0)" ::: "memory");
            __builtin_amdgcn_s_setprio(1);
            if (jh == 0) {
#pragma unroll
                for (int h = 0; h < 2; h++)
#pragma unroll
                    for (int ii = 0; ii < 4; ii++)
#pragma unroll
                        for (int jj = 0; jj < 2; jj++)
                            acc[ih * 4 + ii][jj] =
                                __builtin_amdgcn_mfma_f32_16x16x32_bf16(
                                    af[ii][h], bf0[jj][h],
                                    acc[ih * 4 + ii][jj], 0, 0, 0);
            } else {
#pragma unroll
                for (int h = 0; h < 2; h++)
#pragma unroll
                    for (int ii = 0; ii < 4; ii++)
#pragma unroll
                        for (int jj = 0; jj < 2; jj++)
                            acc[ih * 4 + ii][2 + jj] =
                                __builtin_amdgcn_mfma_f32_16x16x32_bf16(
                                    af[ii][h], bf1[jj][h],
                                    acc[ih * 4 + ii][2 + jj], 0, 0, 0);
            }
            __builtin_amdgcn_s_setprio(0);
            // NO post-MFMA barrier (r19): see hazard ledger in header.
        }
    }

    // Epilogue: per (i,rg) row, chunk-max over the 64 cols (4 j-frags x 16
    // l15 lanes), P in fp8, stats write. No LDS use -> no barrier needed.
    // Pbuf layout [i][tid][rg]: one dwordx4 store per i.
    u32* Pt = Pbuf + ((size_t)((b * 16 + mblk) * 16 + nblk)) * 16384;
    int ch = nblk * 4 + wn;
    float2* Sp = statsP + ((size_t)(b * 64 + ch)) * 4096;
    int mbase = mblk * 256 + wm * 128;
#pragma unroll
    for (int i = 0; i < 8; i++) {
        u32x4 pk;
#pragma unroll
        for (int rg = 0; rg < 4; rg++) {
            float v0 = acc[i][0][rg], v1 = acc[i][1][rg];
            float v2 = acc[i][2][rg], v3 = acc[i][3][rg];
            float Mt = fmaxf(fmaxf(v0, v1), fmaxf(v2, v3));
            Mt = dpp_max16(Mt);  // uniform over the 16 l15 lanes
            float e8 = Mt - 8.0f;  // x256 pre-scale for fp8 range
            float p0 = fexp2(v0 - e8), p1 = fexp2(v1 - e8);
            float p2 = fexp2(v2 - e8), p3 = fexp2(v3 - e8);
            pk[rg] = fp8x4_pack(p0, p1, p2, p3);
            float L = dpp_sum16(p0 + p1 + p2 + p3);
            if (l15 == 0)
                Sp[mbase + i * 16 + quad * 4 + rg] =
                    make_float2(Mt, L * 0.00390625f);  // true L_ch
        }
        *(u32x4*)&Pt[i * 2048 + tid * 4] = pk;
    }
}

// ---------------------------------------------------------------------------
// c = M + log2(Z) per row. Separate kernel (r10: fusing into colsum = 64x
// redundancy, +10us; r7: retained-array version spilled). grid 32 x 256.
// ---------------------------------------------------------------------------
__global__ void reduce_stats2(const float2* __restrict__ statsP,
                              float* __restrict__ cstat) {
    int t = blockIdx.x * 256 + threadIdx.x;
    int b = t >> 12, m = t & 4095;
    const float2* sp = statsP + (size_t)b * 64 * 4096 + m;
    float M = -INFINITY;
#pragma unroll 4
    for (int ch = 0; ch < 64; ch++) M = fmaxf(M, sp[(size_t)ch * 4096].x);
    float Z = 0.f;
#pragma unroll 4
    for (int ch = 0; ch < 64; ch++) {
        float2 p = sp[(size_t)ch * 4096];
        Z += p.y * fexp2(p.x - M);
    }
    cstat[t] = M + __log2f(Z);
}

// ---------------------------------------------------------------------------
// Weighted column sums v3 (Pbuf layout [i][tid][rg] -> dwordx4 loads):
// S[n] += sum_m P_fp8[m,n] * exp2(Mt[m]-8-c[m]). F-SKIP (2^-58): dropped
// mass/col <= 4096*256*2^-58 = 2^-38, scale err <= 3.6e-3.
// grid (nblk=16, mgrp=8 (2 mblks each), b=2), 512 threads: thread tid holds
// the SAME (m,n) cells it wrote in pass 1.
// ---------------------------------------------------------------------------
__global__ __launch_bounds__(512) void colsum(
    const u32* __restrict__ Pbuf, const float2* __restrict__ statsP,
    const float* __restrict__ cstat, float* __restrict__ Sg) {
    int tid = threadIdx.x, lane = tid & 63, wid = tid >> 6;
    int quad = lane >> 4, l15 = lane & 15;
    int wm = wid >> 2, wn = wid & 3;
    int nblk = blockIdx.x, mgrp = blockIdx.y, b = blockIdx.z;
    int ch = nblk * 4 + wn;
    const float2* Sp = statsP + ((size_t)(b * 64 + ch)) * 4096;
    const float* Cp = cstat + (size_t)b * 4096;
    float cp[4] = {0.f, 0.f, 0.f, 0.f};
    for (int mb = 0; mb < 2; mb++) {
        int mblk = mgrp * 2 + mb;
        const u32* Pt =
            Pbuf + ((size_t)((b * 16 + mblk) * 16 + nblk)) * 16384;
#pragma unroll
        for (int i = 0; i < 8; i++) {
            int r0 = mblk * 256 + wm * 128 + i * 16 + quad * 4;
            float4 s01 = *(const float4*)&Sp[r0];      // (M0,L0,M1,L1)
            float4 s23 = *(const float4*)&Sp[r0 + 2];  // (M2,L2,M3,L3)
            float4 cv = *(const float4*)&Cp[r0];
            float fv[4] = {fexp2(s01.x - 8.0f - cv.x),
                           fexp2(s01.z - 8.0f - cv.y),
                           fexp2(s23.x - 8.0f - cv.z),
                           fexp2(s23.z - 8.0f - cv.w)};
            float fm = fmaxf(fmaxf(fv[0], fv[1]), fmaxf(fv[2], fv[3]));
            if (fm > 3.469446951953614e-18f) {  // 2^-58: see header comment
                u32x4 e4 = *(const u32x4*)&Pt[i * 2048 + tid * 4];
#pragma unroll
                for (int rg = 0; rg < 4; rg++) {
                    u32 e = e4[rg];
                    cp[0] += FP8_DEC(e, 0) * fv[rg];
                    cp[1] += FP8_DEC(e, 1) * fv[rg];
                    cp[2] += FP8_DEC(e, 2) * fv[rg];
                    cp[3] += FP8_DEC(e, 3) * fv[rg];
                }
            }
        }
    }
#pragma unroll
    for (int j = 0; j < 4; j++) {
        float s = cp[j];
        s += __shfl_xor(s, 16);
        s += __shfl_xor(s, 32);
        if (lane < 16)
            atomicAdd(&Sg[b * 4096 + nblk * 256 + wn * 64 + j * 16 + l15], s);
    }
}

// ---------------------------------------------------------------------------
// Final: out = relu(BN((V*rowscale) . Wo^T + bo)) + X  (fp32 out)
// 64x128 tiles, grid (128, 4). m0 in [0,8192) == flat (b,m).
// ---------------------------------------------------------------------------
__global__ __launch_bounds__(256) void gemm_final(
    const u16* __restrict__ A, const u16* __restrict__ Bt,
    const float* __restrict__ Sg, const float* __restrict__ bo,
    const float* __restrict__ g, const float* __restrict__ bb,
    const float* __restrict__ mean, const float* __restrict__ var,
    const float* __restrict__ X, float* __restrict__ out) {
    __shared__ __align__(16) u16 As[4096];
    __shared__ __align__(16) u16 Bs[8192];
    int tid = threadIdx.x;
    int m0 = blockIdx.x * 64, n0 = blockIdx.y * 128;
    f32x4 acc[2][4];
#pragma unroll
    for (int i = 0; i < 2; i++)
#pragma unroll
        for (int j = 0; j < 4; j++) acc[i][j] = (f32x4){0.f, 0.f, 0.f, 0.f};
    gemm512_r64(A + (size_t)m0 * 512, Bt + (size_t)n0 * 512, As, Bs, acc, tid);
    int lane = tid & 63, quad = lane >> 4, l15 = lane & 15;
    int wm = tid >> 7, wn = (tid >> 6) & 1;
    float sc[2][4];
#pragma unroll
    for (int i = 0; i < 2; i++) {
        float4 s = *(const float4*)&Sg[m0 + wm * 32 + i * 16 + quad * 4];
        float v[4] = {s.x, s.y, s.z, s.w};
#pragma unroll
        for (int rg = 0; rg < 4; rg++) sc[i][rg] = v[rg] / (1e-9f + v[rg]);
    }
#pragma unroll
    for (int j = 0; j < 4; j++) {
        int n = n0 + wn * 64 + j * 16 + l15;
        float aj = rsqrtf(var[n] + 1e-5f) * g[n];
        float cj = bb[n] - mean[n] * aj;
        float bj = bo[n];
#pragma unroll
        for (int i = 0; i < 2; i++)
#pragma unroll
            for (int rg = 0; rg < 4; rg++) {
                int m = m0 + wm * 32 + i * 16 + quad * 4 + rg;
                float x = acc[i][j][rg] * sc[i][rg] + bj;
                float y = x * aj + cj;
                out[(size_t)m * 512 + n] = fmaxf(y, 0.f) + X[(size_t)m * 512 + n];
            }
    }
}

// ---------------------------------------------------------------------------
extern "C" void kernel_launch(void* const* d_in, const int* in_sizes, int n_in,
                              void* d_out, int out_size, void* d_ws, size_t ws_size,
                              hipStream_t stream) {
    const float* X  = (const float*)d_in[0];
    const float* Wq = (const float*)d_in[1];
    const float* Wk = (const float*)d_in[2];
    const float* Wv = (const float*)d_in[3];
    const float* Wo = (const float*)d_in[4];
    const float* bq = (const float*)d_in[5];
    const float* bk = (const float*)d_in[6];
    const float* bv = (const float*)d_in[7];
    const float* bo = (const float*)d_in[8];
    const float* g    = (const float*)d_in[9];
    const float* bb   = (const float*)d_in[10];
    const float* mean = (const float*)d_in[11];
    const float* var  = (const float*)d_in[12];
    float* out = (float*)d_out;

    char* ws = (char*)d_ws;
    u16* Xb  = (u16*)(ws + 0);                    // 8 MB
    u16* Wqt = (u16*)(ws + 8388608);              // 4x512KB (Wq,Wk,Wv,Wo)
    u16* Wot = (u16*)(ws + 9961472);
    u16* Qb  = (u16*)(ws + 10485760);             // Q,K,V contiguous 3x8MB
    u16* Kb  = (u16*)(ws + 18874368);
    u16* Vb  = (u16*)(ws + 27262976);
    float2* statsP = (float2*)(ws + 35651584);    // [b][64][4096] f2 = 4 MB
    float* Sg      = (float*)(ws + 39845888);     // 32 KB
    float* cstat   = (float*)(ws + 39878656);     // 32 KB
    u32* Pbuf      = (u32*)(ws + 39911424);       // 32 MB fp8 P

    prep<<<5121, 256, 0, stream>>>(X, Wq, Wk, Wv, Wo, Xb, Wqt, Wqt + 262144,
                                   Wqt + 524288, Wot, Sg);
    gemm_qkv<<<dim3(64, 4, 3), 256, 0, stream>>>(Xb, Wqt, bq, bk, bv, Qb);
    attn_pass1p<<<dim3(16, 16, 2), 512, 0, stream>>>(Qb, Kb, statsP, Pbuf);
    reduce_stats2<<<32, 256, 0, stream>>>(statsP, cstat);
    colsum<<<dim3(16, 8, 2), 512, 0, stream>>>(Pbuf, statsP, cstat, Sg);
    gemm_final<<<dim3(128, 4), 256, 0, stream>>>(Vb, Wot, Sg, bo, g, bb, mean, var,
                                                 X, out);
}

// Round 5
// 200.546 us; speedup vs baseline: 1.0240x; 1.0090x over previous
//
#include <hip/hip_runtime.h>
#include <hip/hip_bf16.h>

typedef unsigned short u16;
typedef unsigned int u32;
typedef __attribute__((ext_vector_type(8))) short short8;
typedef __attribute__((ext_vector_type(4))) float f32x4;
typedef __attribute__((ext_vector_type(4))) unsigned int u32x4;

__device__ __forceinline__ u16 f2bf(float f) {
    union { float f; unsigned u; } v; v.f = f;
    unsigned r = v.u + 0x7fffu + ((v.u >> 16) & 1u);
    return (u16)(r >> 16);
}

__device__ __forceinline__ float fexp2(float x) {
#if __has_builtin(__builtin_amdgcn_exp2f)
    return __builtin_amdgcn_exp2f(x);
#else
    return __expf(x * 0.6931471805599453f);
#endif
}

// ---------------------------------------------------------------------------
// DPP 16-lane butterfly (r15): masks {1,2,7,15} are GF(2)-independent ->
// valid butterfly over each contiguous 16-lane row.
// ---------------------------------------------------------------------------
template <int CTRL>
__device__ __forceinline__ float fdpp(float x) {
    int xi = __builtin_bit_cast(int, x);
    int r = __builtin_amdgcn_update_dpp(0, xi, CTRL, 0xF, 0xF, true);
    return __builtin_bit_cast(float, r);
}
__device__ __forceinline__ float dpp_max16(float m) {
    m = fmaxf(m, fdpp<0xB1>(m));   // xor 1
    m = fmaxf(m, fdpp<0x4E>(m));   // xor 2
    m = fmaxf(m, fdpp<0x141>(m));  // xor 7 (row_half_mirror)
    m = fmaxf(m, fdpp<0x140>(m));  // xor 15 (row_mirror)
    return m;
}
__device__ __forceinline__ float dpp_sum16(float s) {
    s += fdpp<0xB1>(s);
    s += fdpp<0x4E>(s);
    s += fdpp<0x141>(s);
    s += fdpp<0x140>(s);
    return s;
}

// ---------------------------------------------------------------------------
// fp8 e4m3 pack/unpack (P pre-scaled x256; r9-r13 absmax 0.078).
// ---------------------------------------------------------------------------
#if __has_builtin(__builtin_amdgcn_cvt_pk_fp8_f32) && \
    __has_builtin(__builtin_amdgcn_cvt_f32_fp8)
#define FP8_HW 1
#else
#define FP8_HW 0
#endif

#if !FP8_HW
__device__ __forceinline__ u32 sw_fp8(float x) {  // x in [0, 448]
    union { float f; u32 u; } v; v.f = x;
    int E = (int)(v.u >> 23) - 127;
    if (x < 0.001953125f) return 0;
    if (E < -6) return (u32)(x * 512.0f + 0.5f);
    u32 m = v.u & 0x7fffffu;
    u32 r = (m + 0x80000u) >> 20;
    u32 bits = ((u32)(E + 7) << 3) + r;
    return bits > 0x7eu ? 0x7eu : bits;
}
__device__ __forceinline__ float sw_fp8d(u32 b) {
    u32 e = (b >> 3) & 15u, m = b & 7u;
    if (e == 0) return (float)m * 0.001953125f;
    union { u32 u; float f; } v; v.u = ((e + 120u) << 23) | (m << 20);
    return v.f;
}
#endif

__device__ __forceinline__ u32 fp8x4_pack(float p0, float p1, float p2, float p3) {
#if FP8_HW
    u32 v = (u32)__builtin_amdgcn_cvt_pk_fp8_f32(p0, p1, 0, false);
    v = (u32)__builtin_amdgcn_cvt_pk_fp8_f32(p2, p3, (int)v, true);
    return v;
#else
    return sw_fp8(p0) | (sw_fp8(p1) << 8) | (sw_fp8(p2) << 16) | (sw_fp8(p3) << 24);
#endif
}

#if FP8_HW
#define FP8_DEC(v, s) __builtin_amdgcn_cvt_f32_fp8((int)(v), (s))
#else
#define FP8_DEC(v, s) sw_fp8d(((v) >> ((s) * 8)) & 0xffu)
#endif

// async 16B global->LDS DMA (m97 pattern).
__device__ __forceinline__ void async_cp16(const u16* g, u16* l) {
    __builtin_amdgcn_global_load_lds(
        (const __attribute__((address_space(1))) void*)g,
        (__attribute__((address_space(3))) void*)l, 16, 0, 0);
}

__device__ __forceinline__ short8 mfma_ld(const u16* base, int off) {
    return *(const short8*)&base[off];
}

// ---------------------------------------------------------------------------
// Staging helpers for the 8-phase 256x256 core (T3+T4 schedule).
// Half-tiles: A-half(ih) = wins wm'*16 + ih*8 + [0,8); B-half(jh) = wins
// wn'*8 + jh*4 + [0,4). Each wave stages 2 wins (1 KiB each) per half.
// LDS dest is wave-uniform base + lane*16 (global_load_lds constraint);
// the XOR swizzle lives in the per-lane GLOBAL source address (m173 pattern).
// ---------------------------------------------------------------------------
__device__ __forceinline__ void stage_half_A(const u16* __restrict__ Q,
                                             u16* dst, int kn, int half,
                                             int wid, int srow, int scol) {
#pragma unroll
    for (int c = 0; c < 2; c++) {
        int win = (wid >> 2) * 16 + half * 8 + (wid & 3) * 2 + c;
        async_cp16(Q + (size_t)(win * 8 + srow) * 512 + kn + scol,
                   dst + win * 512);
    }
}
__device__ __forceinline__ void stage_half_B(const u16* __restrict__ K,
                                             u16* dst, int kn, int half,
                                             int wid, int srow, int scol) {
#pragma unroll
    for (int c = 0; c < 2; c++) {
        int win = (wid >> 1) * 8 + half * 4 + (wid & 1) * 2 + c;
        async_cp16(K + (size_t)(win * 8 + srow) * 512 + kn + scol,
                   dst + win * 512);
    }
}

// ---------------------------------------------------------------------------
// Shared 256x256x512 8-phase core (r17-verified; r19's 1-barrier variant
// REGRESSED 52->65us: symmetric waves have no role-split, skew+setprio
// created convoys -- keep the 2-barrier lockstep). 8 waves (2Mx4N), BK=64,
// 128 KiB LDS dbuf, counted vmcnt (never 0 in loop): half-tiles of kt+1 at
// A0,B0@p0, B1@p1, A1@p2; waits vmcnt(6)@p1, vmcnt(2)@p3. Gray-code phases
// (0,0)->(0,1)->(1,1)->(1,0), register-held B-halves (24 ds_read/kt/wave).
// A.B^T into acc[8][4]; acc element (i,j,rg) is C row
// m0+wm*128+i*16+quad*4+rg, col n0+wn*64+j*16+l15.
// ---------------------------------------------------------------------------
__device__ __forceinline__ void core256(const u16* __restrict__ A,
                                        const u16* __restrict__ B,
                                        u16* As0, u16* As1,
                                        u16* Bs0, u16* Bs1,
                                        f32x4 acc[8][4], int tid) {
    int lane = tid & 63, wid = tid >> 6;
    int quad = lane >> 4, l15 = lane & 15;
    int wm = wid >> 2, wn = wid & 3;
    int Gw = lane ^ ((lane >> 3) & 7);
    int srow = Gw >> 3, scol = (Gw & 7) * 8;
    int rl = l15 & 7, winl = l15 >> 3;
    int Pr[2];
#pragma unroll
    for (int h = 0; h < 2; h++)
        Pr[h] = (rl * 8 + ((quad + h * 4) ^ rl)) * 8;

    // Prologue: stage tile 0 fully, single full drain (only one in kernel).
    stage_half_A(A, As0, 0, 0, wid, srow, scol);
    stage_half_B(B, Bs0, 0, 0, wid, srow, scol);
    stage_half_B(B, Bs0, 0, 1, wid, srow, scol);
    stage_half_A(A, As0, 0, 1, wid, srow, scol);
    asm volatile("s_waitcnt vmcnt(0)" ::: "memory");
    __builtin_amdgcn_s_barrier();
    asm volatile("" ::: "memory");

    for (int kt = 0; kt < 8; ++kt) {
        const u16* Ac = (kt & 1) ? As1 : As0;
        const u16* Bc = (kt & 1) ? Bs1 : Bs0;
        u16* An = (kt & 1) ? As0 : As1;
        u16* Bn = (kt & 1) ? Bs0 : Bs1;
        int kn = (kt + 1) * 64;
        bool pf = (kt < 7);
        short8 af[4][2], bf0[2][2], bf1[2][2];
#pragma unroll
        for (int ph = 0; ph < 4; ++ph) {
            // Gray code: (ih,jh) = (0,0),(0,1),(1,1),(1,0)
            const int ih = ph >> 1;
            const int jh = (ph ^ (ph >> 1)) & 1;
            if (ph == 0) {
#pragma unroll
                for (int h = 0; h < 2; h++)
#pragma unroll
                    for (int ii = 0; ii < 4; ii++)
                        af[ii][h] = mfma_ld(
                            Ac, (wm * 16 + ii * 2 + winl) * 512 + Pr[h]);
#pragma unroll
                for (int h = 0; h < 2; h++)
#pragma unroll
                    for (int jj = 0; jj < 2; jj++)
                        bf0[jj][h] = mfma_ld(
                            Bc, (wn * 8 + jj * 2 + winl) * 512 + Pr[h]);
            } else if (ph == 1) {
#pragma unroll
                for (int h = 0; h < 2; h++)
#pragma unroll
                    for (int jj = 0; jj < 2; jj++)
                        bf1[jj][h] = mfma_ld(
                            Bc, (wn * 8 + 4 + jj * 2 + winl) * 512 + Pr[h]);
            } else if (ph == 2) {
#pragma unroll
                for (int h = 0; h < 2; h++)
#pragma unroll
                    for (int ii = 0; ii < 4; ii++)
                        af[ii][h] = mfma_ld(
                            Ac, (wm * 16 + 8 + ii * 2 + winl) * 512 + Pr[h]);
            }
            if (pf) {
                if (ph == 0) {
                    stage_half_A(A, An, kn, 0, wid, srow, scol);
                    stage_half_B(B, Bn, kn, 0, wid, srow, scol);
                } else if (ph == 1) {
                    stage_half_B(B, Bn, kn, 1, wid, srow, scol);
                } else if (ph == 2) {
                    stage_half_A(A, An, kn, 1, wid, srow, scol);
                }
            }
            if (ph == 1) {
                if (pf) asm volatile("s_waitcnt vmcnt(6)" ::: "memory");
                else    asm volatile("s_waitcnt vmcnt(0)" ::: "memory");
            }
            if (ph == 3) asm volatile("s_waitcnt vmcnt(2)" ::: "memory");
            asm volatile("" ::: "memory");
            __builtin_amdgcn_s_barrier();
            asm volatile("s_waitcnt lgkmcnt(0)" ::: "memory");
            __builtin_amdgcn_s_setprio(1);
            if (jh == 0) {
#pragma unroll
                for (int h = 0; h < 2; h++)
#pragma unroll
                    for (int ii = 0; ii < 4; ii++)
#pragma unroll
                        for (int jj = 0; jj < 2; jj++)
                            acc[ih * 4 + ii][jj] =
                                __builtin_amdgcn_mfma_f32_16x16x32_bf16(
                                    af[ii][h], bf0[jj][h],
                                    acc[ih * 4 + ii][jj], 0, 0, 0);
            } else {
#pragma unroll
                for (int h = 0; h < 2; h++)
#pragma unroll
                    for (int ii = 0; ii < 4; ii++)
#pragma unroll
                        for (int jj = 0; jj < 2; jj++)
                            acc[ih * 4 + ii][2 + jj] =
                                __builtin_amdgcn_mfma_f32_16x16x32_bf16(
                                    af[ii][h], bf1[jj][h],
                                    acc[ih * 4 + ii][2 + jj], 0, 0, 0);
            }
            __builtin_amdgcn_s_setprio(0);
            asm volatile("" ::: "memory");
            __builtin_amdgcn_s_barrier();
            asm volatile("" ::: "memory");
        }
    }
}

// 64x128x512 variant (A 64 rows). As: 4096 u16, Bs: 8192 u16.
__device__ __forceinline__ void gemm512_r64(const u16* __restrict__ A,
                                            const u16* __restrict__ B,
                                            u16* As, u16* Bs,
                                            f32x4 acc[2][4], int tid) {
    const int lane = tid & 63, w = tid >> 6;
    const int quad = lane >> 4, l15 = lane & 15;
    const int wm = tid >> 7, wn = (tid >> 6) & 1;
    const int Gw = lane ^ ((lane >> 3) & 7);
    const int srow = Gw >> 3;
    const int scol = (Gw & 7) * 8;
    const int rl = l15 & 7;
    const int winl = l15 >> 3;
    int Pr[2];
#pragma unroll
    for (int h = 0; h < 2; h++)
        Pr[h] = (rl * 8 + ((quad + h * 4) ^ rl)) * 8;
    const int winA0 = (wm * 32) >> 3, winB0 = (wn * 64) >> 3;
    for (int k0 = 0; k0 < 512; k0 += 64) {
        __syncthreads();
#pragma unroll
        for (int t = 0; t < 2; t++) {
            int win = w * 2 + t;
            async_cp16(A + (size_t)(win * 8 + srow) * 512 + k0 + scol,
                       As + win * 512);
        }
#pragma unroll
        for (int t = 0; t < 4; t++) {
            int win = w * 4 + t;
            async_cp16(B + (size_t)(win * 8 + srow) * 512 + k0 + scol,
                       Bs + win * 512);
        }
        __syncthreads();
#pragma unroll
        for (int h = 0; h < 2; h++) {
            short8 af[2], bfr[4];
#pragma unroll
            for (int i = 0; i < 2; i++)
                af[i] = mfma_ld(As, (winA0 + i * 2 + winl) * 512 + Pr[h]);
#pragma unroll
            for (int j = 0; j < 4; j++)
                bfr[j] = mfma_ld(Bs, (winB0 + j * 2 + winl) * 512 + Pr[h]);
#pragma unroll
            for (int i = 0; i < 2; i++)
#pragma unroll
                for (int j = 0; j < 4; j++)
                    acc[i][j] = __builtin_amdgcn_mfma_f32_16x16x32_bf16(
                        af[i], bfr[j], acc[i][j], 0, 0, 0);
        }
    }
}

// ---------------------------------------------------------------------------
// Fused prep: [0,4096) convert X->bf16; [4096,5120) transpose weights;
// 5120: zero Sg (per-launch, graph-safe).
// ---------------------------------------------------------------------------
__global__ void prep(const float* __restrict__ X, const float* __restrict__ W0,
                     const float* __restrict__ W1, const float* __restrict__ W2,
                     const float* __restrict__ W3, u16* __restrict__ Xb,
                     u16* __restrict__ T0, u16* __restrict__ T1,
                     u16* __restrict__ T2, u16* __restrict__ T3,
                     float* __restrict__ Sg) {
    __shared__ float tile[32][33];
    int id = blockIdx.x, tid = threadIdx.x;
    if (id == 5120) {
        float4 z = {0.f, 0.f, 0.f, 0.f};
#pragma unroll
        for (int t = 0; t < 8; t++) ((float4*)Sg)[tid + t * 256] = z;
        return;
    }
    if (id < 4096) {
        int idx = (id * 256 + tid) * 4;
        float4 v = *(const float4*)&X[idx];
        ushort4 o;
        o.x = f2bf(v.x); o.y = f2bf(v.y); o.z = f2bf(v.z); o.w = f2bf(v.w);
        *(ushort4*)&Xb[idx] = o;
        return;
    }
    int t = id - 4096;
    int z = t >> 8, rem = t & 255;
    int bo_ = (rem & 15) * 32, bi = (rem >> 4) * 32;
    const float* src; u16* dst;
    switch (z) {
        case 0: src = W0; dst = T0; break;
        case 1: src = W1; dst = T1; break;
        case 2: src = W2; dst = T2; break;
        default: src = W3; dst = T3; break;
    }
    int tx = tid & 31, ty = tid >> 5;
#pragma unroll
    for (int s = 0; s < 4; s++) {
        int i = bi + ty + s * 8;
        tile[ty + s * 8][tx] = src[i * 512 + bo_ + tx];
    }
    __syncthreads();
#pragma unroll
    for (int s = 0; s < 4; s++) {
        int o = bo_ + ty + s * 8;
        dst[o * 512 + bi + tx] = f2bf(tile[tx][ty + s * 8]);
    }
}

// ---------------------------------------------------------------------------
// Fused QKV projection v2 (r20): 256x256 8-phase core (same verified
// schedule as attn pass-1) replacing the old 128x128 full-drain structure.
// r19 accounting: non-attn kernels sum to ~150us; qkv (12.9 GF at the old
// 2-barrier structure, K=512 where it is weakest) is the likely elephant.
// Grid (32, 2, 3), 512 threads, 128 KiB LDS, 1 block/CU. Accumulation order
// per output element unchanged (kt asc, h asc) -> Q/K/V bit-identical.
// z==0 (Q) scaled by log2(e) -> base-2 score domain.
// ---------------------------------------------------------------------------
__global__ __launch_bounds__(512, 2) void gemm_qkv(
    const u16* __restrict__ Xb, const u16* __restrict__ Wall,
    const float* __restrict__ bq, const float* __restrict__ bk,
    const float* __restrict__ bv, u16* __restrict__ Qall) {
    __shared__ __align__(16) u16 As[2][16384];
    __shared__ __align__(16) u16 Bs[2][16384];
    int tid = threadIdx.x;
    int m0 = blockIdx.x * 256, n0 = blockIdx.y * 256, z = blockIdx.z;
    const u16* A = Xb + (size_t)m0 * 512;
    const u16* B = Wall + (size_t)z * 262144 + (size_t)n0 * 512;
    f32x4 acc[8][4];
#pragma unroll
    for (int i = 0; i < 8; i++)
#pragma unroll
        for (int j = 0; j < 4; j++) acc[i][j] = (f32x4){0.f, 0.f, 0.f, 0.f};
    core256(A, B, &As[0][0], &As[1][0], &Bs[0][0], &Bs[1][0], acc, tid);

    const float* bias = (z == 0) ? bq : (z == 1) ? bk : bv;
    const float qs = (z == 0) ? 1.44269504088896340736f : 1.0f;
    u16* C = Qall + (size_t)z * 4194304;
    int lane = tid & 63, wid = tid >> 6;
    int quad = lane >> 4, l15 = lane & 15;
    int wm = wid >> 2, wn = wid & 3;
#pragma unroll
    for (int j = 0; j < 4; j++) {
        int n = n0 + wn * 64 + j * 16 + l15;
        float bvv = bias[n];
#pragma unroll
        for (int i = 0; i < 8; i++)
#pragma unroll
            for (int rg = 0; rg < 4; rg++) {
                int m = m0 + wm * 128 + i * 16 + quad * 4 + rg;
                C[(size_t)m * 512 + n] = f2bf((acc[i][j][rg] + bvv) * qs);
            }
    }
}

// ---------------------------------------------------------------------------
// Pass 1 (r20 = r17 revert): 256x256 tile, 8-phase 2-barrier lockstep core +
// softmax epilogue. r19's 1-barrier experiment regressed (52->65us, convoy
// effects); the 2-barrier lockstep is the verified optimum of this structure.
// Epilogue: per (i,rg) row, chunk-max over 64 cols via DPP butterfly,
// P = exp2(s - Mt + 8) fp8x4 in Pbuf[i][tid][rg] (dwordx4), stats (Mt, L/256).
// Grid (16, 16, 2), 512 threads.
// ---------------------------------------------------------------------------
__global__ __launch_bounds__(512, 2) void attn_pass1p(
    const u16* __restrict__ Qb, const u16* __restrict__ Kb,
    float2* __restrict__ statsP, u32* __restrict__ Pbuf) {
    __shared__ __align__(16) u16 As[2][16384];
    __shared__ __align__(16) u16 Bs[2][16384];
    int tid = threadIdx.x;
    int mblk = blockIdx.x, nblk = blockIdx.y, b = blockIdx.z;
    const u16* Q = Qb + ((size_t)(b * 4096 + mblk * 256)) * 512;
    const u16* K = Kb + ((size_t)(b * 4096 + nblk * 256)) * 512;
    int lane = tid & 63, wid = tid >> 6;
    int quad = lane >> 4, l15 = lane & 15;
    int wm = wid >> 2, wn = wid & 3;

    f32x4 acc[8][4];
#pragma unroll
    for (int i = 0; i < 8; i++)
#pragma unroll
        for (int j = 0; j < 4; j++) acc[i][j] = (f32x4){0.f, 0.f, 0.f, 0.f};
    core256(Q, K, &As[0][0], &As[1][0], &Bs[0][0], &Bs[1][0], acc, tid);

    // Epilogue: per (i,rg) row, chunk-max over the 64 cols (4 j-frags x 16
    // l15 lanes), P in fp8, stats write. No LDS use -> no barrier needed.
    u32* Pt = Pbuf + ((size_t)((b * 16 + mblk) * 16 + nblk)) * 16384;
    int ch = nblk * 4 + wn;
    float2* Sp = statsP + ((size_t)(b * 64 + ch)) * 4096;
    int mbase = mblk * 256 + wm * 128;
#pragma unroll
    for (int i = 0; i < 8; i++) {
        u32x4 pk;
#pragma unroll
        for (int rg = 0; rg < 4; rg++) {
            float v0 = acc[i][0][rg], v1 = acc[i][1][rg];
            float v2 = acc[i][2][rg], v3 = acc[i][3][rg];
            float Mt = fmaxf(fmaxf(v0, v1), fmaxf(v2, v3));
            Mt = dpp_max16(Mt);  // uniform over the 16 l15 lanes
            float e8 = Mt - 8.0f;  // x256 pre-scale for fp8 range
            float p0 = fexp2(v0 - e8), p1 = fexp2(v1 - e8);
            float p2 = fexp2(v2 - e8), p3 = fexp2(v3 - e8);
            pk[rg] = fp8x4_pack(p0, p1, p2, p3);
            float L = dpp_sum16(p0 + p1 + p2 + p3);
            if (l15 == 0)
                Sp[mbase + i * 16 + quad * 4 + rg] =
                    make_float2(Mt, L * 0.00390625f);  // true L_ch
        }
        *(u32x4*)&Pt[i * 2048 + tid * 4] = pk;
    }
}

// ---------------------------------------------------------------------------
// c = M + log2(Z) per row. Separate kernel (r10: fusing into colsum = 64x
// redundancy, +10us; r7: retained-array version spilled). grid 32 x 256.
// ---------------------------------------------------------------------------
__global__ void reduce_stats2(const float2* __restrict__ statsP,
                              float* __restrict__ cstat) {
    int t = blockIdx.x * 256 + threadIdx.x;
    int b = t >> 12, m = t & 4095;
    const float2* sp = statsP + (size_t)b * 64 * 4096 + m;
    float M = -INFINITY;
#pragma unroll 4
    for (int ch = 0; ch < 64; ch++) M = fmaxf(M, sp[(size_t)ch * 4096].x);
    float Z = 0.f;
#pragma unroll 4
    for (int ch = 0; ch < 64; ch++) {
        float2 p = sp[(size_t)ch * 4096];
        Z += p.y * fexp2(p.x - M);
    }
    cstat[t] = M + __log2f(Z);
}

// ---------------------------------------------------------------------------
// Weighted column sums (Pbuf layout [i][tid][rg] -> dwordx4 loads):
// S[n] += sum_m P_fp8[m,n] * exp2(Mt[m]-8-c[m]). F-SKIP (2^-58): dropped
// mass/col <= 4096*256*2^-58 = 2^-38, scale err <= 3.6e-3.
// grid (nblk=16, mgrp=8 (2 mblks each), b=2), 512 threads: thread tid holds
// the SAME (m,n) cells it wrote in pass 1.
// ---------------------------------------------------------------------------
__global__ __launch_bounds__(512) void colsum(
    const u32* __restrict__ Pbuf, const float2* __restrict__ statsP,
    const float* __restrict__ cstat, float* __restrict__ Sg) {
    int tid = threadIdx.x, lane = tid & 63, wid = tid >> 6;
    int quad = lane >> 4, l15 = lane & 15;
    int wm = wid >> 2, wn = wid & 3;
    int nblk = blockIdx.x, mgrp = blockIdx.y, b = blockIdx.z;
    int ch = nblk * 4 + wn;
    const float2* Sp = statsP + ((size_t)(b * 64 + ch)) * 4096;
    const float* Cp = cstat + (size_t)b * 4096;
    float cp[4] = {0.f, 0.f, 0.f, 0.f};
    for (int mb = 0; mb < 2; mb++) {
        int mblk = mgrp * 2 + mb;
        const u32* Pt =
            Pbuf + ((size_t)((b * 16 + mblk) * 16 + nblk)) * 16384;
#pragma unroll
        for (int i = 0; i < 8; i++) {
            int r0 = mblk * 256 + wm * 128 + i * 16 + quad * 4;
            float4 s01 = *(const float4*)&Sp[r0];      // (M0,L0,M1,L1)
            float4 s23 = *(const float4*)&Sp[r0 + 2];  // (M2,L2,M3,L3)
            float4 cv = *(const float4*)&Cp[r0];
            float fv[4] = {fexp2(s01.x - 8.0f - cv.x),
                           fexp2(s01.z - 8.0f - cv.y),
                           fexp2(s23.x - 8.0f - cv.z),
                           fexp2(s23.z - 8.0f - cv.w)};
            float fm = fmaxf(fmaxf(fv[0], fv[1]), fmaxf(fv[2], fv[3]));
            if (fm > 3.469446951953614e-18f) {  // 2^-58: see header comment
                u32x4 e4 = *(const u32x4*)&Pt[i * 2048 + tid * 4];
#pragma unroll
                for (int rg = 0; rg < 4; rg++) {
                    u32 e = e4[rg];
                    cp[0] += FP8_DEC(e, 0) * fv[rg];
                    cp[1] += FP8_DEC(e, 1) * fv[rg];
                    cp[2] += FP8_DEC(e, 2) * fv[rg];
                    cp[3] += FP8_DEC(e, 3) * fv[rg];
                }
            }
        }
    }
#pragma unroll
    for (int j = 0; j < 4; j++) {
        float s = cp[j];
        s += __shfl_xor(s, 16);
        s += __shfl_xor(s, 32);
        if (lane < 16)
            atomicAdd(&Sg[b * 4096 + nblk * 256 + wn * 64 + j * 16 + l15], s);
    }
}

// ---------------------------------------------------------------------------
// Final: out = relu(BN((V*rowscale) . Wo^T + bo)) + X  (fp32 out)
// 64x128 tiles, grid (128, 4). m0 in [0,8192) == flat (b,m).
// ---------------------------------------------------------------------------
__global__ __launch_bounds__(256) void gemm_final(
    const u16* __restrict__ A, const u16* __restrict__ Bt,
    const float* __restrict__ Sg, const float* __restrict__ bo,
    const float* __restrict__ g, const float* __restrict__ bb,
    const float* __restrict__ mean, const float* __restrict__ var,
    const float* __restrict__ X, float* __restrict__ out) {
    __shared__ __align__(16) u16 As[4096];
    __shared__ __align__(16) u16 Bs[8192];
    int tid = threadIdx.x;
    int m0 = blockIdx.x * 64, n0 = blockIdx.y * 128;
    f32x4 acc[2][4];
#pragma unroll
    for (int i = 0; i < 2; i++)
#pragma unroll
        for (int j = 0; j < 4; j++) acc[i][j] = (f32x4){0.f, 0.f, 0.f, 0.f};
    gemm512_r64(A + (size_t)m0 * 512, Bt + (size_t)n0 * 512, As, Bs, acc, tid);
    int lane = tid & 63, quad = lane >> 4, l15 = lane & 15;
    int wm = tid >> 7, wn = (tid >> 6) & 1;
    float sc[2][4];
#pragma unroll
    for (int i = 0; i < 2; i++) {
        float4 s = *(const float4*)&Sg[m0 + wm * 32 + i * 16 + quad * 4];
        float v[4] = {s.x, s.y, s.z, s.w};
#pragma unroll
        for (int rg = 0; rg < 4; rg++) sc[i][rg] = v[rg] / (1e-9f + v[rg]);
    }
#pragma unroll
    for (int j = 0; j < 4; j++) {
        int n = n0 + wn * 64 + j * 16 + l15;
        float aj = rsqrtf(var[n] + 1e-5f) * g[n];
        float cj = bb[n] - mean[n] * aj;
        float bj = bo[n];
#pragma unroll
        for (int i = 0; i < 2; i++)
#pragma unroll
            for (int rg = 0; rg < 4; rg++) {
                int m = m0 + wm * 32 + i * 16 + quad * 4 + rg;
                float x = acc[i][j][rg] * sc[i][rg] + bj;
                float y = x * aj + cj;
                out[(size_t)m * 512 + n] = fmaxf(y, 0.f) + X[(size_t)m * 512 + n];
            }
    }
}

// ---------------------------------------------------------------------------
extern "C" void kernel_launch(void* const* d_in, const int* in_sizes, int n_in,
                              void* d_out, int out_size, void* d_ws, size_t ws_size,
                              hipStream_t stream) {
    const float* X  = (const float*)d_in[0];
    const float* Wq = (const float*)d_in[1];
    const float* Wk = (const float*)d_in[2];
    const float* Wv = (const float*)d_in[3];
    const float* Wo = (const float*)d_in[4];
    const float* bq = (const float*)d_in[5];
    const float* bk = (const float*)d_in[6];
    const float* bv = (const float*)d_in[7];
    const float* bo = (const float*)d_in[8];
    const float* g    = (const float*)d_in[9];
    const float* bb   = (const float*)d_in[10];
    const float* mean = (const float*)d_in[11];
    const float* var  = (const float*)d_in[12];
    float* out = (float*)d_out;

    char* ws = (char*)d_ws;
    u16* Xb  = (u16*)(ws + 0);                    // 8 MB
    u16* Wqt = (u16*)(ws + 8388608);              // 4x512KB (Wq,Wk,Wv,Wo)
    u16* Wot = (u16*)(ws + 9961472);
    u16* Qb  = (u16*)(ws + 10485760);             // Q,K,V contiguous 3x8MB
    u16* Kb  = (u16*)(ws + 18874368);
    u16* Vb  = (u16*)(ws + 27262976);
    float2* statsP = (float2*)(ws + 35651584);    // [b][64][4096] f2 = 4 MB
    float* Sg      = (float*)(ws + 39845888);     // 32 KB
    float* cstat   = (float*)(ws + 39878656);     // 32 KB
    u32* Pbuf      = (u32*)(ws + 39911424);       // 32 MB fp8 P

    prep<<<5121, 256, 0, stream>>>(X, Wq, Wk, Wv, Wo, Xb, Wqt, Wqt + 262144,
                                   Wqt + 524288, Wot, Sg);
    gemm_qkv<<<dim3(32, 2, 3), 512, 0, stream>>>(Xb, Wqt, bq, bk, bv, Qb);
    attn_pass1p<<<dim3(16, 16, 2), 512, 0, stream>>>(Qb, Kb, statsP, Pbuf);
    reduce_stats2<<<32, 256, 0, stream>>>(statsP, cstat);
    colsum<<<dim3(16, 8, 2), 512, 0, stream>>>(Pbuf, statsP, cstat, Sg);
    gemm_final<<<dim3(128, 4), 256, 0, stream>>>(Vb, Wot, Sg, bo, g, bb, mean, var,
                                                 X, out);
}

// Round 6
// 199.761 us; speedup vs baseline: 1.0280x; 1.0039x over previous
//
#include <hip/hip_runtime.h>
#include <hip/hip_bf16.h>

typedef unsigned short u16;
typedef unsigned int u32;
typedef __attribute__((ext_vector_type(8))) short short8;
typedef __attribute__((ext_vector_type(4))) float f32x4;
typedef __attribute__((ext_vector_type(4))) unsigned int u32x4;

__device__ __forceinline__ u16 f2bf(float f) {
    union { float f; unsigned u; } v; v.f = f;
    unsigned r = v.u + 0x7fffu + ((v.u >> 16) & 1u);
    return (u16)(r >> 16);
}

__device__ __forceinline__ float fexp2(float x) {
#if __has_builtin(__builtin_amdgcn_exp2f)
    return __builtin_amdgcn_exp2f(x);
#else
    return __expf(x * 0.6931471805599453f);
#endif
}

// ---------------------------------------------------------------------------
// DPP 16-lane butterfly (r15): masks {1,2,7,15} are GF(2)-independent ->
// valid butterfly over each contiguous 16-lane row.
// ---------------------------------------------------------------------------
template <int CTRL>
__device__ __forceinline__ float fdpp(float x) {
    int xi = __builtin_bit_cast(int, x);
    int r = __builtin_amdgcn_update_dpp(0, xi, CTRL, 0xF, 0xF, true);
    return __builtin_bit_cast(float, r);
}
__device__ __forceinline__ float dpp_max16(float m) {
    m = fmaxf(m, fdpp<0xB1>(m));   // xor 1
    m = fmaxf(m, fdpp<0x4E>(m));   // xor 2
    m = fmaxf(m, fdpp<0x141>(m));  // xor 7 (row_half_mirror)
    m = fmaxf(m, fdpp<0x140>(m));  // xor 15 (row_mirror)
    return m;
}
__device__ __forceinline__ float dpp_sum16(float s) {
    s += fdpp<0xB1>(s);
    s += fdpp<0x4E>(s);
    s += fdpp<0x141>(s);
    s += fdpp<0x140>(s);
    return s;
}

// ---------------------------------------------------------------------------
// fp8 e4m3 pack/unpack (P pre-scaled x256; r9-r13 absmax 0.078).
// ---------------------------------------------------------------------------
#if __has_builtin(__builtin_amdgcn_cvt_pk_fp8_f32) && \
    __has_builtin(__builtin_amdgcn_cvt_f32_fp8)
#define FP8_HW 1
#else
#define FP8_HW 0
#endif

#if !FP8_HW
__device__ __forceinline__ u32 sw_fp8(float x) {  // x in [0, 448]
    union { float f; u32 u; } v; v.f = x;
    int E = (int)(v.u >> 23) - 127;
    if (x < 0.001953125f) return 0;
    if (E < -6) return (u32)(x * 512.0f + 0.5f);
    u32 m = v.u & 0x7fffffu;
    u32 r = (m + 0x80000u) >> 20;
    u32 bits = ((u32)(E + 7) << 3) + r;
    return bits > 0x7eu ? 0x7eu : bits;
}
__device__ __forceinline__ float sw_fp8d(u32 b) {
    u32 e = (b >> 3) & 15u, m = b & 7u;
    if (e == 0) return (float)m * 0.001953125f;
    union { u32 u; float f; } v; v.u = ((e + 120u) << 23) | (m << 20);
    return v.f;
}
#endif

__device__ __forceinline__ u32 fp8x4_pack(float p0, float p1, float p2, float p3) {
#if FP8_HW
    u32 v = (u32)__builtin_amdgcn_cvt_pk_fp8_f32(p0, p1, 0, false);
    v = (u32)__builtin_amdgcn_cvt_pk_fp8_f32(p2, p3, (int)v, true);
    return v;
#else
    return sw_fp8(p0) | (sw_fp8(p1) << 8) | (sw_fp8(p2) << 16) | (sw_fp8(p3) << 24);
#endif
}

#if FP8_HW
#define FP8_DEC(v, s) __builtin_amdgcn_cvt_f32_fp8((int)(v), (s))
#else
#define FP8_DEC(v, s) sw_fp8d(((v) >> ((s) * 8)) & 0xffu)
#endif

// async 16B global->LDS DMA (m97 pattern).
__device__ __forceinline__ void async_cp16(const u16* g, u16* l) {
    __builtin_amdgcn_global_load_lds(
        (const __attribute__((address_space(1))) void*)g,
        (__attribute__((address_space(3))) void*)l, 16, 0, 0);
}

__device__ __forceinline__ short8 mfma_ld(const u16* base, int off) {
    return *(const short8*)&base[off];
}

// ---------------------------------------------------------------------------
// Staging helpers for the 8-phase 256x256 core (T3+T4 schedule).
// Half-tiles: A-half(ih) = wins wm'*16 + ih*8 + [0,8); B-half(jh) = wins
// wn'*8 + jh*4 + [0,4). Each wave stages 2 wins (1 KiB each) per half.
// LDS dest is wave-uniform base + lane*16 (global_load_lds constraint);
// the XOR swizzle lives in the per-lane GLOBAL source address (m173 pattern).
// ---------------------------------------------------------------------------
__device__ __forceinline__ void stage_half_A(const u16* __restrict__ Q,
                                             u16* dst, int kn, int half,
                                             int wid, int srow, int scol) {
#pragma unroll
    for (int c = 0; c < 2; c++) {
        int win = (wid >> 2) * 16 + half * 8 + (wid & 3) * 2 + c;
        async_cp16(Q + (size_t)(win * 8 + srow) * 512 + kn + scol,
                   dst + win * 512);
    }
}
__device__ __forceinline__ void stage_half_B(const u16* __restrict__ K,
                                             u16* dst, int kn, int half,
                                             int wid, int srow, int scol) {
#pragma unroll
    for (int c = 0; c < 2; c++) {
        int win = (wid >> 1) * 8 + half * 4 + (wid & 1) * 2 + c;
        async_cp16(K + (size_t)(win * 8 + srow) * 512 + kn + scol,
                   dst + win * 512);
    }
}

// ---------------------------------------------------------------------------
// Fragment load / MFMA helpers (all-static indices; SROA-friendly).
// ---------------------------------------------------------------------------
__device__ __forceinline__ void ld_a(const u16* S, short8 af[4][2], int row0,
                                     int winl, const int* Pr) {
#pragma unroll
    for (int h = 0; h < 2; h++)
#pragma unroll
        for (int ii = 0; ii < 4; ii++)
            af[ii][h] = mfma_ld(S, (row0 + ii * 2 + winl) * 512 + Pr[h]);
}
__device__ __forceinline__ void ld_b(const u16* S, short8 bf[2][2], int row0,
                                     int winl, const int* Pr) {
#pragma unroll
    for (int h = 0; h < 2; h++)
#pragma unroll
        for (int jj = 0; jj < 2; jj++)
            bf[jj][h] = mfma_ld(S, (row0 + jj * 2 + winl) * 512 + Pr[h]);
}
__device__ __forceinline__ void mfma8(f32x4 acc[8][4], int i0, int j0,
                                      const short8 af[4][2],
                                      const short8 bf[2][2]) {
#pragma unroll
    for (int h = 0; h < 2; h++)
#pragma unroll
        for (int ii = 0; ii < 4; ii++)
#pragma unroll
            for (int jj = 0; jj < 2; jj++)
                acc[i0 + ii][j0 + jj] = __builtin_amdgcn_mfma_f32_16x16x32_bf16(
                    af[ii][h], bf[jj][h], acc[i0 + ii][j0 + jj], 0, 0, 0);
}

// ---------------------------------------------------------------------------
// One K-tile of the shifted 8-phase schedule (r21). r20 post-mortem: LDS
// reads (~4600 cyc/CU/kt) and MFMA (~4100) are BALANCED pipes, but the old
// {reads -> lgkmcnt(0) -> MFMA} phase body serialized them (sum ~8700 cyc/kt,
// MfmaUtil capped ~27%). Shifted schedule: each phase issues the NEXT phase's
// ds_reads after the entry barrier, then MFMAs on operands read LAST phase --
// reads stay outstanding across the MFMA cluster (per-wave LDS/MFMA overlap
// inside the unchanged 2-barrier lockstep; r19 showed breaking lockstep
// regresses). No explicit lgkmcnt: plain C++ LDS loads let the compiler emit
// fine counted waits before first use (next phase). Read sets per phase:
// {ph0: bf1(4), ph1: afH(8), ph2: 0, ph3: next afL+bf0(12)}. Visibility:
// afH follows vmcnt(6)+barrier@ph1 (publishes this buffer's A1, staged
// prev-kt ph2); the ph3 12-reads follow vmcnt(2)+barrier@ph3 (publishes next
// buffer's A0,B0,B1). bf0 is register-double-buffered (BF0C/BF0N by kt
// parity -- static via template, rule #20). Staging issue points and the
// vmcnt ledger are IDENTICAL to r17/r20 (never 0 in loop). Accumulation
// order per acc element unchanged (kt asc, h asc) -> bit-identical output.
// ---------------------------------------------------------------------------
template <int KT>
__device__ __forceinline__ void kt_step(
    const u16* __restrict__ A, const u16* __restrict__ B,
    const u16* Ac, const u16* Bc, u16* An, u16* Bn,
    short8 afL[4][2], short8 afH[4][2], short8 bf0c[2][2], short8 bf0n[2][2],
    short8 bf1[2][2], f32x4 acc[8][4], int wid, int srow, int scol, int wm,
    int wn, int winl, const int* Pr) {
    const int kn = (KT + 1) * 64;
    constexpr bool pf = (KT < 7);
    // ---- ph0: issue bf1; MFMA(afL, bf0c) ----
    if (pf) {
        stage_half_A(A, An, kn, 0, wid, srow, scol);
        stage_half_B(B, Bn, kn, 0, wid, srow, scol);
    }
    __builtin_amdgcn_s_barrier();
    asm volatile("" ::: "memory");
    ld_b(Bc, bf1, wn * 8 + 4, winl, Pr);
    __builtin_amdgcn_s_setprio(1);
    mfma8(acc, 0, 0, afL, bf0c);
    __builtin_amdgcn_s_setprio(0);
    asm volatile("" ::: "memory");
    __builtin_amdgcn_s_barrier();
    asm volatile("" ::: "memory");
    // ---- ph1: issue afH; MFMA(afL, bf1) ----
    if (pf) {
        stage_half_B(B, Bn, kn, 1, wid, srow, scol);
        asm volatile("s_waitcnt vmcnt(6)" ::: "memory");
    } else {
        asm volatile("s_waitcnt vmcnt(0)" ::: "memory");
    }
    __builtin_amdgcn_s_barrier();
    asm volatile("" ::: "memory");
    ld_a(Ac, afH, wm * 16 + 8, winl, Pr);
    __builtin_amdgcn_s_setprio(1);
    mfma8(acc, 0, 2, afL, bf1);
    __builtin_amdgcn_s_setprio(0);
    asm volatile("" ::: "memory");
    __builtin_amdgcn_s_barrier();
    asm volatile("" ::: "memory");
    // ---- ph2: (no reads); MFMA(afH, bf1) ----
    if (pf) stage_half_A(A, An, kn, 1, wid, srow, scol);
    __builtin_amdgcn_s_barrier();
    asm volatile("" ::: "memory");
    __builtin_amdgcn_s_setprio(1);
    mfma8(acc, 4, 2, afH, bf1);
    __builtin_amdgcn_s_setprio(0);
    asm volatile("" ::: "memory");
    __builtin_amdgcn_s_barrier();
    asm volatile("" ::: "memory");
    // ---- ph3: issue next-kt afL + bf0n; MFMA(afH, bf0c) ----
    asm volatile("s_waitcnt vmcnt(2)" ::: "memory");
    __builtin_amdgcn_s_barrier();
    asm volatile("" ::: "memory");
    if (pf) {
        ld_a(An, afL, wm * 16, winl, Pr);
        ld_b(Bn, bf0n, wn * 8, winl, Pr);
    }
    __builtin_amdgcn_s_setprio(1);
    mfma8(acc, 4, 0, afH, bf0c);
    __builtin_amdgcn_s_setprio(0);
    asm volatile("" ::: "memory");
    __builtin_amdgcn_s_barrier();
    asm volatile("" ::: "memory");
}

// ---------------------------------------------------------------------------
// Shared 256x256x512 shifted 8-phase core (r21). 8 waves (2Mx4N), BK=64,
// 128 KiB LDS dbuf, counted vmcnt, 2 barriers/phase lockstep. A.B^T into
// acc[8][4]; acc (i,j,rg) = C row m0+wm*128+i*16+quad*4+rg,
// col n0+wn*64+j*16+l15.
// ---------------------------------------------------------------------------
__device__ __forceinline__ void core256(const u16* __restrict__ A,
                                        const u16* __restrict__ B,
                                        u16* As0, u16* As1,
                                        u16* Bs0, u16* Bs1,
                                        f32x4 acc[8][4], int tid) {
    int lane = tid & 63, wid = tid >> 6;
    int quad = lane >> 4, l15 = lane & 15;
    int wm = wid >> 2, wn = wid & 3;
    int Gw = lane ^ ((lane >> 3) & 7);
    int srow = Gw >> 3, scol = (Gw & 7) * 8;
    int rl = l15 & 7, winl = l15 >> 3;
    int Pr[2];
#pragma unroll
    for (int h = 0; h < 2; h++)
        Pr[h] = (rl * 8 + ((quad + h * 4) ^ rl)) * 8;

    short8 afL[4][2], afH[4][2], bf0a[2][2], bf0b[2][2], bf1[2][2];

    // Prologue: stage tile 0 fully, single full drain (only one in kernel),
    // then preload kt0-ph0 operands.
    stage_half_A(A, As0, 0, 0, wid, srow, scol);
    stage_half_B(B, Bs0, 0, 0, wid, srow, scol);
    stage_half_B(B, Bs0, 0, 1, wid, srow, scol);
    stage_half_A(A, As0, 0, 1, wid, srow, scol);
    asm volatile("s_waitcnt vmcnt(0)" ::: "memory");
    __builtin_amdgcn_s_barrier();
    asm volatile("" ::: "memory");
    ld_a(As0, afL, wm * 16, winl, Pr);
    ld_b(Bs0, bf0a, wn * 8, winl, Pr);

    kt_step<0>(A, B, As0, Bs0, As1, Bs1, afL, afH, bf0a, bf0b, bf1, acc,
               wid, srow, scol, wm, wn, winl, Pr);
    kt_step<1>(A, B, As1, Bs1, As0, Bs0, afL, afH, bf0b, bf0a, bf1, acc,
               wid, srow, scol, wm, wn, winl, Pr);
    kt_step<2>(A, B, As0, Bs0, As1, Bs1, afL, afH, bf0a, bf0b, bf1, acc,
               wid, srow, scol, wm, wn, winl, Pr);
    kt_step<3>(A, B, As1, Bs1, As0, Bs0, afL, afH, bf0b, bf0a, bf1, acc,
               wid, srow, scol, wm, wn, winl, Pr);
    kt_step<4>(A, B, As0, Bs0, As1, Bs1, afL, afH, bf0a, bf0b, bf1, acc,
               wid, srow, scol, wm, wn, winl, Pr);
    kt_step<5>(A, B, As1, Bs1, As0, Bs0, afL, afH, bf0b, bf0a, bf1, acc,
               wid, srow, scol, wm, wn, winl, Pr);
    kt_step<6>(A, B, As0, Bs0, As1, Bs1, afL, afH, bf0a, bf0b, bf1, acc,
               wid, srow, scol, wm, wn, winl, Pr);
    kt_step<7>(A, B, As1, Bs1, As0, Bs0, afL, afH, bf0b, bf0a, bf1, acc,
               wid, srow, scol, wm, wn, winl, Pr);
}

// 64x128x512 variant (A 64 rows). As: 4096 u16, Bs: 8192 u16.
__device__ __forceinline__ void gemm512_r64(const u16* __restrict__ A,
                                            const u16* __restrict__ B,
                                            u16* As, u16* Bs,
                                            f32x4 acc[2][4], int tid) {
    const int lane = tid & 63, w = tid >> 6;
    const int quad = lane >> 4, l15 = lane & 15;
    const int wm = tid >> 7, wn = (tid >> 6) & 1;
    const int Gw = lane ^ ((lane >> 3) & 7);
    const int srow = Gw >> 3;
    const int scol = (Gw & 7) * 8;
    const int rl = l15 & 7;
    const int winl = l15 >> 3;
    int Pr[2];
#pragma unroll
    for (int h = 0; h < 2; h++)
        Pr[h] = (rl * 8 + ((quad + h * 4) ^ rl)) * 8;
    const int winA0 = (wm * 32) >> 3, winB0 = (wn * 64) >> 3;
    for (int k0 = 0; k0 < 512; k0 += 64) {
        __syncthreads();
#pragma unroll
        for (int t = 0; t < 2; t++) {
            int win = w * 2 + t;
            async_cp16(A + (size_t)(win * 8 + srow) * 512 + k0 + scol,
                       As + win * 512);
        }
#pragma unroll
        for (int t = 0; t < 4; t++) {
            int win = w * 4 + t;
            async_cp16(B + (size_t)(win * 8 + srow) * 512 + k0 + scol,
                       Bs + win * 512);
        }
        __syncthreads();
#pragma unroll
        for (int h = 0; h < 2; h++) {
            short8 af[2], bfr[4];
#pragma unroll
            for (int i = 0; i < 2; i++)
                af[i] = mfma_ld(As, (winA0 + i * 2 + winl) * 512 + Pr[h]);
#pragma unroll
            for (int j = 0; j < 4; j++)
                bfr[j] = mfma_ld(Bs, (winB0 + j * 2 + winl) * 512 + Pr[h]);
#pragma unroll
            for (int i = 0; i < 2; i++)
#pragma unroll
                for (int j = 0; j < 4; j++)
                    acc[i][j] = __builtin_amdgcn_mfma_f32_16x16x32_bf16(
                        af[i], bfr[j], acc[i][j], 0, 0, 0);
        }
    }
}

// ---------------------------------------------------------------------------
// Fused prep: [0,4096) convert X->bf16; [4096,5120) transpose weights;
// 5120: zero Sg (per-launch, graph-safe).
// ---------------------------------------------------------------------------
__global__ void prep(const float* __restrict__ X, const float* __restrict__ W0,
                     const float* __restrict__ W1, const float* __restrict__ W2,
                     const float* __restrict__ W3, u16* __restrict__ Xb,
                     u16* __restrict__ T0, u16* __restrict__ T1,
                     u16* __restrict__ T2, u16* __restrict__ T3,
                     float* __restrict__ Sg) {
    __shared__ float tile[32][33];
    int id = blockIdx.x, tid = threadIdx.x;
    if (id == 5120) {
        float4 z = {0.f, 0.f, 0.f, 0.f};
#pragma unroll
        for (int t = 0; t < 8; t++) ((float4*)Sg)[tid + t * 256] = z;
        return;
    }
    if (id < 4096) {
        int idx = (id * 256 + tid) * 4;
        float4 v = *(const float4*)&X[idx];
        ushort4 o;
        o.x = f2bf(v.x); o.y = f2bf(v.y); o.z = f2bf(v.z); o.w = f2bf(v.w);
        *(ushort4*)&Xb[idx] = o;
        return;
    }
    int t = id - 4096;
    int z = t >> 8, rem = t & 255;
    int bo_ = (rem & 15) * 32, bi = (rem >> 4) * 32;
    const float* src; u16* dst;
    switch (z) {
        case 0: src = W0; dst = T0; break;
        case 1: src = W1; dst = T1; break;
        case 2: src = W2; dst = T2; break;
        default: src = W3; dst = T3; break;
    }
    int tx = tid & 31, ty = tid >> 5;
#pragma unroll
    for (int s = 0; s < 4; s++) {
        int i = bi + ty + s * 8;
        tile[ty + s * 8][tx] = src[i * 512 + bo_ + tx];
    }
    __syncthreads();
#pragma unroll
    for (int s = 0; s < 4; s++) {
        int o = bo_ + ty + s * 8;
        dst[o * 512 + bi + tx] = f2bf(tile[tx][ty + s * 8]);
    }
}

// ---------------------------------------------------------------------------
// Fused QKV projection (256x256 shifted 8-phase core). Grid (32, 2, 3),
// 512 threads. z==0 (Q) scaled by log2(e) -> base-2 score domain.
// ---------------------------------------------------------------------------
__global__ __launch_bounds__(512, 2) void gemm_qkv(
    const u16* __restrict__ Xb, const u16* __restrict__ Wall,
    const float* __restrict__ bq, const float* __restrict__ bk,
    const float* __restrict__ bv, u16* __restrict__ Qall) {
    __shared__ __align__(16) u16 As[2][16384];
    __shared__ __align__(16) u16 Bs[2][16384];
    int tid = threadIdx.x;
    int m0 = blockIdx.x * 256, n0 = blockIdx.y * 256, z = blockIdx.z;
    const u16* A = Xb + (size_t)m0 * 512;
    const u16* B = Wall + (size_t)z * 262144 + (size_t)n0 * 512;
    f32x4 acc[8][4];
#pragma unroll
    for (int i = 0; i < 8; i++)
#pragma unroll
        for (int j = 0; j < 4; j++) acc[i][j] = (f32x4){0.f, 0.f, 0.f, 0.f};
    core256(A, B, &As[0][0], &As[1][0], &Bs[0][0], &Bs[1][0], acc, tid);

    const float* bias = (z == 0) ? bq : (z == 1) ? bk : bv;
    const float qs = (z == 0) ? 1.44269504088896340736f : 1.0f;
    u16* C = Qall + (size_t)z * 4194304;
    int lane = tid & 63, wid = tid >> 6;
    int quad = lane >> 4, l15 = lane & 15;
    int wm = wid >> 2, wn = wid & 3;
#pragma unroll
    for (int j = 0; j < 4; j++) {
        int n = n0 + wn * 64 + j * 16 + l15;
        float bvv = bias[n];
#pragma unroll
        for (int i = 0; i < 8; i++)
#pragma unroll
            for (int rg = 0; rg < 4; rg++) {
                int m = m0 + wm * 128 + i * 16 + quad * 4 + rg;
                C[(size_t)m * 512 + n] = f2bf((acc[i][j][rg] + bvv) * qs);
            }
    }
}

// ---------------------------------------------------------------------------
// Pass 1 (256x256 shifted 8-phase core + softmax epilogue). Epilogue: per
// (i,rg) row, chunk-max over 64 cols via DPP butterfly, P = exp2(s - Mt + 8)
// fp8x4 in Pbuf[i][tid][rg] (dwordx4), stats (Mt, L/256).
// Grid (16, 16, 2), 512 threads.
// ---------------------------------------------------------------------------
__global__ __launch_bounds__(512, 2) void attn_pass1p(
    const u16* __restrict__ Qb, const u16* __restrict__ Kb,
    float2* __restrict__ statsP, u32* __restrict__ Pbuf) {
    __shared__ __align__(16) u16 As[2][16384];
    __shared__ __align__(16) u16 Bs[2][16384];
    int tid = threadIdx.x;
    int mblk = blockIdx.x, nblk = blockIdx.y, b = blockIdx.z;
    const u16* Q = Qb + ((size_t)(b * 4096 + mblk * 256)) * 512;
    const u16* K = Kb + ((size_t)(b * 4096 + nblk * 256)) * 512;
    int lane = tid & 63, wid = tid >> 6;
    int quad = lane >> 4, l15 = lane & 15;
    int wm = wid >> 2, wn = wid & 3;

    f32x4 acc[8][4];
#pragma unroll
    for (int i = 0; i < 8; i++)
#pragma unroll
        for (int j = 0; j < 4; j++) acc[i][j] = (f32x4){0.f, 0.f, 0.f, 0.f};
    core256(Q, K, &As[0][0], &As[1][0], &Bs[0][0], &Bs[1][0], acc, tid);

    // Epilogue: per (i,rg) row, chunk-max over the 64 cols (4 j-frags x 16
    // l15 lanes), P in fp8, stats write. No LDS use -> no barrier needed.
    u32* Pt = Pbuf + ((size_t)((b * 16 + mblk) * 16 + nblk)) * 16384;
    int ch = nblk * 4 + wn;
    float2* Sp = statsP + ((size_t)(b * 64 + ch)) * 4096;
    int mbase = mblk * 256 + wm * 128;
#pragma unroll
    for (int i = 0; i < 8; i++) {
        u32x4 pk;
#pragma unroll
        for (int rg = 0; rg < 4; rg++) {
            float v0 = acc[i][0][rg], v1 = acc[i][1][rg];
            float v2 = acc[i][2][rg], v3 = acc[i][3][rg];
            float Mt = fmaxf(fmaxf(v0, v1), fmaxf(v2, v3));
            Mt = dpp_max16(Mt);  // uniform over the 16 l15 lanes
            float e8 = Mt - 8.0f;  // x256 pre-scale for fp8 range
            float p0 = fexp2(v0 - e8), p1 = fexp2(v1 - e8);
            float p2 = fexp2(v2 - e8), p3 = fexp2(v3 - e8);
            pk[rg] = fp8x4_pack(p0, p1, p2, p3);
            float L = dpp_sum16(p0 + p1 + p2 + p3);
            if (l15 == 0)
                Sp[mbase + i * 16 + quad * 4 + rg] =
                    make_float2(Mt, L * 0.00390625f);  // true L_ch
        }
        *(u32x4*)&Pt[i * 2048 + tid * 4] = pk;
    }
}

// ---------------------------------------------------------------------------
// c = M + log2(Z) per row. Separate kernel (r10: fusing into colsum = 64x
// redundancy, +10us; r7: retained-array version spilled). grid 32 x 256.
// ---------------------------------------------------------------------------
__global__ void reduce_stats2(const float2* __restrict__ statsP,
                              float* __restrict__ cstat) {
    int t = blockIdx.x * 256 + threadIdx.x;
    int b = t >> 12, m = t & 4095;
    const float2* sp = statsP + (size_t)b * 64 * 4096 + m;
    float M = -INFINITY;
#pragma unroll 4
    for (int ch = 0; ch < 64; ch++) M = fmaxf(M, sp[(size_t)ch * 4096].x);
    float Z = 0.f;
#pragma unroll 4
    for (int ch = 0; ch < 64; ch++) {
        float2 p = sp[(size_t)ch * 4096];
        Z += p.y * fexp2(p.x - M);
    }
    cstat[t] = M + __log2f(Z);
}

// ---------------------------------------------------------------------------
// Weighted column sums (Pbuf layout [i][tid][rg] -> dwordx4 loads):
// S[n] += sum_m P_fp8[m,n] * exp2(Mt[m]-8-c[m]). F-SKIP (2^-58): dropped
// mass/col <= 4096*256*2^-58 = 2^-38, scale err <= 3.6e-3.
// grid (nblk=16, mgrp=8 (2 mblks each), b=2), 512 threads: thread tid holds
// the SAME (m,n) cells it wrote in pass 1.
// ---------------------------------------------------------------------------
__global__ __launch_bounds__(512) void colsum(
    const u32* __restrict__ Pbuf, const float2* __restrict__ statsP,
    const float* __restrict__ cstat, float* __restrict__ Sg) {
    int tid = threadIdx.x, lane = tid & 63, wid = tid >> 6;
    int quad = lane >> 4, l15 = lane & 15;
    int wm = wid >> 2, wn = wid & 3;
    int nblk = blockIdx.x, mgrp = blockIdx.y, b = blockIdx.z;
    int ch = nblk * 4 + wn;
    const float2* Sp = statsP + ((size_t)(b * 64 + ch)) * 4096;
    const float* Cp = cstat + (size_t)b * 4096;
    float cp[4] = {0.f, 0.f, 0.f, 0.f};
    for (int mb = 0; mb < 2; mb++) {
        int mblk = mgrp * 2 + mb;
        const u32* Pt =
            Pbuf + ((size_t)((b * 16 + mblk) * 16 + nblk)) * 16384;
#pragma unroll
        for (int i = 0; i < 8; i++) {
            int r0 = mblk * 256 + wm * 128 + i * 16 + quad * 4;
            float4 s01 = *(const float4*)&Sp[r0];      // (M0,L0,M1,L1)
            float4 s23 = *(const float4*)&Sp[r0 + 2];  // (M2,L2,M3,L3)
            float4 cv = *(const float4*)&Cp[r0];
            float fv[4] = {fexp2(s01.x - 8.0f - cv.x),
                           fexp2(s01.z - 8.0f - cv.y),
                           fexp2(s23.x - 8.0f - cv.z),
                           fexp2(s23.z - 8.0f - cv.w)};
            float fm = fmaxf(fmaxf(fv[0], fv[1]), fmaxf(fv[2], fv[3]));
            if (fm > 3.469446951953614e-18f) {  // 2^-58: see header comment
                u32x4 e4 = *(const u32x4*)&Pt[i * 2048 + tid * 4];
#pragma unroll
                for (int rg = 0; rg < 4; rg++) {
                    u32 e = e4[rg];
                    cp[0] += FP8_DEC(e, 0) * fv[rg];
                    cp[1] += FP8_DEC(e, 1) * fv[rg];
                    cp[2] += FP8_DEC(e, 2) * fv[rg];
                    cp[3] += FP8_DEC(e, 3) * fv[rg];
                }
            }
        }
    }
#pragma unroll
    for (int j = 0; j < 4; j++) {
        float s = cp[j];
        s += __shfl_xor(s, 16);
        s += __shfl_xor(s, 32);
        if (lane < 16)
            atomicAdd(&Sg[b * 4096 + nblk * 256 + wn * 64 + j * 16 + l15], s);
    }
}

// ---------------------------------------------------------------------------
// Final: out = relu(BN((V*rowscale) . Wo^T + bo)) + X  (fp32 out)
// 64x128 tiles, grid (128, 4). m0 in [0,8192) == flat (b,m).
// ---------------------------------------------------------------------------
__global__ __launch_bounds__(256) void gemm_final(
    const u16* __restrict__ A, const u16* __restrict__ Bt,
    const float* __restrict__ Sg, const float* __restrict__ bo,
    const float* __restrict__ g, const float* __restrict__ bb,
    const float* __restrict__ mean, const float* __restrict__ var,
    const float* __restrict__ X, float* __restrict__ out) {
    __shared__ __align__(16) u16 As[4096];
    __shared__ __align__(16) u16 Bs[8192];
    int tid = threadIdx.x;
    int m0 = blockIdx.x * 64, n0 = blockIdx.y * 128;
    f32x4 acc[2][4];
#pragma unroll
    for (int i = 0; i < 2; i++)
#pragma unroll
        for (int j = 0; j < 4; j++) acc[i][j] = (f32x4){0.f, 0.f, 0.f, 0.f};
    gemm512_r64(A + (size_t)m0 * 512, Bt + (size_t)n0 * 512, As, Bs, acc, tid);
    int lane = tid & 63, quad = lane >> 4, l15 = lane & 15;
    int wm = tid >> 7, wn = (tid >> 6) & 1;
    float sc[2][4];
#pragma unroll
    for (int i = 0; i < 2; i++) {
        float4 s = *(const float4*)&Sg[m0 + wm * 32 + i * 16 + quad * 4];
        float v[4] = {s.x, s.y, s.z, s.w};
#pragma unroll
        for (int rg = 0; rg < 4; rg++) sc[i][rg] = v[rg] / (1e-9f + v[rg]);
    }
#pragma unroll
    for (int j = 0; j < 4; j++) {
        int n = n0 + wn * 64 + j * 16 + l15;
        float aj = rsqrtf(var[n] + 1e-5f) * g[n];
        float cj = bb[n] - mean[n] * aj;
        float bj = bo[n];
#pragma unroll
        for (int i = 0; i < 2; i++)
#pragma unroll
            for (int rg = 0; rg < 4; rg++) {
                int m = m0 + wm * 32 + i * 16 + quad * 4 + rg;
                float x = acc[i][j][rg] * sc[i][rg] + bj;
                float y = x * aj + cj;
                out[(size_t)m * 512 + n] = fmaxf(y, 0.f) + X[(size_t)m * 512 + n];
            }
    }
}

// ---------------------------------------------------------------------------
extern "C" void kernel_launch(void* const* d_in, const int* in_sizes, int n_in,
                              void* d_out, int out_size, void* d_ws, size_t ws_size,
                              hipStream_t stream) {
    const float* X  = (const float*)d_in[0];
    const float* Wq = (const float*)d_in[1];
    const float* Wk = (const float*)d_in[2];
    const float* Wv = (const float*)d_in[3];
    const float* Wo = (const float*)d_in[4];
    const float* bq = (const float*)d_in[5];
    const float* bk = (const float*)d_in[6];
    const float* bv = (const float*)d_in[7];
    const float* bo = (const float*)d_in[8];
    const float* g    = (const float*)d_in[9];
    const float* bb   = (const float*)d_in[10];
    const float* mean = (const float*)d_in[11];
    const float* var  = (const float*)d_in[12];
    float* out = (float*)d_out;

    char* ws = (char*)d_ws;
    u16* Xb  = (u16*)(ws + 0);                    // 8 MB
    u16* Wqt = (u16*)(ws + 8388608);              // 4x512KB (Wq,Wk,Wv,Wo)
    u16* Wot = (u16*)(ws + 9961472);
    u16* Qb  = (u16*)(ws + 10485760);             // Q,K,V contiguous 3x8MB
    u16* Kb  = (u16*)(ws + 18874368);
    u16* Vb  = (u16*)(ws + 27262976);
    float2* statsP = (float2*)(ws + 35651584);    // [b][64][4096] f2 = 4 MB
    float* Sg      = (float*)(ws + 39845888);     // 32 KB
    float* cstat   = (float*)(ws + 39878656);     // 32 KB
    u32* Pbuf      = (u32*)(ws + 39911424);       // 32 MB fp8 P

    prep<<<5121, 256, 0, stream>>>(X, Wq, Wk, Wv, Wo, Xb, Wqt, Wqt + 262144,
                                   Wqt + 524288, Wot, Sg);
    gemm_qkv<<<dim3(32, 2, 3), 512, 0, stream>>>(Xb, Wqt, bq, bk, bv, Qb);
    attn_pass1p<<<dim3(16, 16, 2), 512, 0, stream>>>(Qb, Kb, statsP, Pbuf);
    reduce_stats2<<<32, 256, 0, stream>>>(statsP, cstat);
    colsum<<<dim3(16, 8, 2), 512, 0, stream>>>(Pbuf, statsP, cstat, Sg);
    gemm_final<<<dim3(128, 4), 256, 0, stream>>>(Vb, Wot, Sg, bo, g, bb, mean, var,
                                                 X, out);
}